// Round 2
// baseline (29988.046 us; speedup 1.0000x reference)
//
#include <hip/hip_runtime.h>
#include <hip/hip_bf16.h>
#include <hip/hip_fp16.h>

#define LL    3630
#define EPSV  1e-5f

typedef short bf16x8 __attribute__((ext_vector_type(8)));
typedef float f32x4  __attribute__((ext_vector_type(4)));

__device__ __forceinline__ float bf2f(__hip_bfloat16 x){ return __bfloat162float(x); }
__device__ __forceinline__ __hip_bfloat16 f2bf(float x){ return __float2bfloat16(x); }
__device__ __forceinline__ float siluf(float x){ return x / (1.f + __expf(-x)); }

// ======================= weight f32 -> bf16 =======================
__global__ __launch_bounds__(256) void convert_weights(
    const float* __restrict__ s0, const float* __restrict__ s1,
    const float* __restrict__ s2, const float* __restrict__ s3,
    const float* __restrict__ s4, const float* __restrict__ s5,
    __hip_bfloat16* __restrict__ dst)
{
  int gid = blockIdx.x*256 + threadIdx.x;
  float v;
  if      (gid <  65536) v = s0[gid];
  else if (gid < 327680) v = s1[gid-65536];
  else if (gid < 458752) v = s2[gid-327680];
  else if (gid < 491520) v = s3[gid-458752];
  else if (gid < 557056) v = s4[gid-491520];
  else if (gid < 622592) v = s5[gid-557056];
  else return;
  dst[gid] = f2bf(v);
}

// ======================= stem =======================
__global__ __launch_bounds__(256) void stem1_kernel(
    const float* __restrict__ x, const float* __restrict__ w,
    const float* __restrict__ g, const float* __restrict__ bb,
    const float* __restrict__ mm, const float* __restrict__ vv,
    float* __restrict__ out, int nb, int b0)
{
  int idx = blockIdx.x*256 + threadIdx.x;
  if (idx >= nb*123904) return;
  int j = idx % 11;
  int i = (idx/11) % 11;
  int t = (idx/121) % 32;
  int c = (idx/(121*32)) % 32;
  int b = idx/(121*32*32);
  const float* xp = x + ((b0+b)*32 + t)*169;
  const float* wp = w + c*9;
  float acc = 0.f;
  #pragma unroll
  for (int di=0; di<3; ++di)
    #pragma unroll
    for (int dj=0; dj<3; ++dj)
      acc += xp[(i+di)*13 + (j+dj)] * wp[di*3+dj];
  float s = g[c]*rsqrtf(vv[c]+EPSV);
  acc = acc*s + (bb[c]-mm[c]*s);
  out[idx] = fmaxf(acc, 0.f);
}

__global__ __launch_bounds__(256) void stem2_kernel(
    const float* __restrict__ h1, const float* __restrict__ w,
    const float* __restrict__ g, const float* __restrict__ bb,
    const float* __restrict__ mm, const float* __restrict__ vv,
    float* __restrict__ out, int nb)
{
  int idx = blockIdx.x*256 + threadIdx.x;
  if (idx >= nb*116160) return;
  int ij = idx % 121;
  int t  = (idx/121) % 30;
  int c  = (idx/(121*30)) % 32;
  int b  = idx/(121*30*32);
  const float* hp = h1 + ((b*32+c)*32)*121 + ij;
  const float* wp = w + c*3;
  float acc = 0.f;
  #pragma unroll
  for (int k=0;k<3;++k) acc += hp[(t+k)*121] * wp[k];
  float s = g[c]*rsqrtf(vv[c]+EPSV);
  acc = acc*s + (bb[c]-mm[c]*s);
  out[idx] = fmaxf(acc, 0.f);
}

__global__ __launch_bounds__(256) void stem3_kernel(
    const float* __restrict__ h2, const float* __restrict__ w,
    __hip_bfloat16* __restrict__ xb, int tokens)
{
  int gid = blockIdx.x*256 + threadIdx.x;
  int cc = gid & 63;
  int tok = gid >> 6;
  if (tok >= tokens) return;
  int ij = tok % 121;
  int t  = (tok/121) % 30;
  int b  = tok/LL;
  const float* hp = h2 + ((long)b*32)*30*121 + t*121 + ij;
  const float* wp = w + cc*32;
  float acc = 0.f;
  #pragma unroll
  for (int ci=0; ci<32; ++ci) acc += hp[ci*3630] * wp[ci];
  xb[(long)tok*64+cc] = f2bf(acc);
}

// ======================= layernorm (dim 64), bf16 in/out =======================
__global__ __launch_bounds__(256) void ln_kernel(
    const __hip_bfloat16* __restrict__ xb, const float* __restrict__ g,
    const float* __restrict__ b2, __hip_bfloat16* __restrict__ out, int tokens)
{
  int wid = threadIdx.x >> 6, lane = threadIdx.x & 63;
  long tok = (long)blockIdx.x*4 + wid;
  if (tok >= tokens) return;
  float v = bf2f(xb[tok*64 + lane]);
  float s = v, q = v*v;
  #pragma unroll
  for (int m=1; m<64; m<<=1){ s += __shfl_xor(s,m); q += __shfl_xor(q,m); }
  float mean = s*(1.f/64.f);
  float var  = q*(1.f/64.f) - mean*mean;
  float o = (v-mean)*rsqrtf(var+EPSV)*g[lane] + b2[lane];
  out[tok*64+lane] = f2bf(o);
}

// ======================= bf16 MFMA GEMM: out[M,N] = A[M,K] @ W[N,K]^T =======================
// EPI 0: split: col<NH -> out1 raw [M,NH]; col>=NH -> out2 silu [M,NH]
// EPI 2: +bias, exact gelu -> out1 [M,N]
// EPI 3: (+bias) + bf16 residual RMW [M,N]
// EPI 4: * gate[M,N] -> out1 [M,N]
template<int EPI>
__global__ __launch_bounds__(256) void gemm_bf16(
    const __hip_bfloat16* __restrict__ A, const __hip_bfloat16* __restrict__ W,
    int K, int N, int NH, int tokens,
    __hip_bfloat16* __restrict__ out1, __hip_bfloat16* __restrict__ out2,
    const float* __restrict__ bias, const __hip_bfloat16* __restrict__ gate,
    __hip_bfloat16* __restrict__ resid)
{
  int w   = threadIdx.x >> 6;
  int lane= threadIdx.x & 63;
  int r16 = lane & 15;
  int kg  = lane >> 4;          // 0..3
  long m0 = (long)blockIdx.x*64 + w*16;
  int  n0 = blockIdx.y*64;
  f32x4 acc[4] = { {0,0,0,0},{0,0,0,0},{0,0,0,0},{0,0,0,0} };
  for (int k0 = 0; k0 < K; k0 += 32){
    bf16x8 a = *reinterpret_cast<const bf16x8*>(A + (m0 + r16)*K + k0 + kg*8);
    #pragma unroll
    for (int f=0; f<4; ++f){
      bf16x8 b = *reinterpret_cast<const bf16x8*>(W + (long)(n0 + f*16 + r16)*K + k0 + kg*8);
      acc[f] = __builtin_amdgcn_mfma_f32_16x16x32_bf16(a, b, acc[f], 0, 0, 0);
    }
  }
  #pragma unroll
  for (int f=0; f<4; ++f){
    int col = n0 + f*16 + r16;
    #pragma unroll
    for (int r=0; r<4; ++r){
      long row = m0 + kg*4 + r;
      if (row >= tokens) continue;
      float v = acc[f][r];
      if (EPI == 0){
        if (col < NH) out1[row*NH + col] = f2bf(v);
        else          out2[row*NH + col - NH] = f2bf(siluf(v));
      } else if (EPI == 2){
        v += bias[col];
        v = 0.5f*v*(1.f + erff(v*0.70710678118f));
        out1[row*N + col] = f2bf(v);
      } else if (EPI == 3){
        if (bias) v += bias[col];
        resid[row*N + col] = f2bf(v + bf2f(resid[row*N + col]));
      } else {
        out1[row*N + col] = f2bf(v * bf2f(gate[row*N + col]));
      }
    }
  }
}

// ======================= depthwise conv3d 3x3x3 SAME + silu =======================
__global__ __launch_bounds__(256) void dwconv3d_kernel(
    const __hip_bfloat16* __restrict__ xs, const float* __restrict__ w,
    const float* __restrict__ bias, __hip_bfloat16* __restrict__ seq, int tokens)
{
  long gid = (long)blockIdx.x*256 + threadIdx.x;
  int c = gid & 127;
  long tok = gid >> 7;
  if (tok >= tokens) return;
  int j  = tok % 11;
  int i2 = (tok/11) % 11;
  int t  = (tok/121) % 30;
  long b = tok/LL;
  const float* wc = w + c*27;
  float acc = bias[c];
  #pragma unroll
  for (int dt=0; dt<3; ++dt){
    int tt = t+dt-1; if (tt<0 || tt>=30) continue;
    #pragma unroll
    for (int di=0; di<3; ++di){
      int ii = i2+di-1; if (ii<0 || ii>=11) continue;
      #pragma unroll
      for (int dj=0; dj<3; ++dj){
        int jj = j+dj-1; if (jj<0 || jj>=11) continue;
        long t2 = (b*30+tt)*121 + ii*11 + jj;
        acc += wc[dt*9+di*3+dj] * bf2f(xs[t2*128 + c]);
      }
    }
  }
  seq[tok*128 + c] = f2bf(siluf(acc));
}

// ======================= fused conv1d(fwd/bwd)+silu + xproj =======================
// grid = 2*nb sequences * 363 chunks of 10 tokens; block 256 (= d)
__global__ __launch_bounds__(256) void mamba_pre_kernel(
    const __hip_bfloat16* __restrict__ xm,   // [nb, L, 256] fwd-order raw x
    const float* __restrict__ cw, const float* __restrict__ cbv,
    const float* __restrict__ xpw,           // [40,256]
    __hip_bfloat16* __restrict__ bc,         // [2nb, L, 32]  (B:0..15, C:16..31)
    float* __restrict__ dtr,                 // [2nb, L, 8]
    int nb)
{
  __shared__ __align__(16) float xcs[10][256];
  int blk = blockIdx.x;
  int s  = blk / 363;
  int ch = blk % 363;
  int p0 = ch*10;
  int b  = s % nb;
  bool fwd = s < nb;
  int d = threadIdx.x;

  float xv[13];
  #pragma unroll
  for (int k=0; k<13; ++k){
    int p = p0 - 3 + k;
    float val = 0.f;
    if (p >= 0 && p < LL){
      int src = fwd ? p : (LL-1-p);
      val = bf2f(xm[((long)b*LL + src)*256 + d]);
    }
    xv[k] = val;
  }
  float w0=cw[d*4], w1=cw[d*4+1], w2=cw[d*4+2], w3=cw[d*4+3], cb=cbv[d];
  #pragma unroll
  for (int t=0; t<10; ++t){
    float xc = w0*xv[t] + w1*xv[t+1] + w2*xv[t+2] + w3*xv[t+3] + cb;
    xcs[t][d] = siluf(xc);
  }
  __syncthreads();
  for (int jj = threadIdx.x; jj < 400; jj += 256){
    int t = jj/40, r = jj%40;
    const float* wr = xpw + r*256;
    float acc = 0.f;
    for (int dd=0; dd<256; dd+=4){
      float4 xq = *reinterpret_cast<const float4*>(&xcs[t][dd]);
      float4 wq = *reinterpret_cast<const float4*>(&wr[dd]);
      acc += xq.x*wq.x + xq.y*wq.y + xq.z*wq.z + xq.w*wq.w;
    }
    long tokg = (long)s*LL + p0 + t;
    if (r < 8) dtr[tokg*8 + r] = acc;
    else       bc[tokg*32 + (r-8)] = f2bf(acc);
  }
}

// ======================= selective scan =======================
// grid 16*nb = s(2nb) * dgrp(8, 32 d each); block 256 (4 waves); lane owns (d, n0..n0+1)
__global__ __launch_bounds__(256) void scan_kernel(
    const __hip_bfloat16* __restrict__ xm,   // [nb, L, 256]
    const float* __restrict__ dtr,           // [2nb, L, 8]
    const __hip_bfloat16* __restrict__ bc,   // [2nb, L, 32]
    const __hip_bfloat16* __restrict__ zm,   // [nb, L, 256] silu'd
    const float* __restrict__ cw, const float* __restrict__ cbv,
    const float* __restrict__ dtw, const float* __restrict__ dtbv,
    const float* __restrict__ Alog, const float* __restrict__ Dv,
    __hip_bfloat16* __restrict__ yb,         // [2nb, L, 256] (zm-gated per dir)
    int nb)
{
  int wid = threadIdx.x >> 6, lane = threadIdx.x & 63;
  int s = blockIdx.x >> 3, dgrp = blockIdx.x & 7;
  int dl = lane >> 3, np = lane & 7;
  int d = dgrp*32 + wid*8 + dl;
  int b = s % nb;
  bool fwd = s < nb;
  int n0 = np*2;
  float a20 = -expf(Alog[d*16+n0  ]) * 1.44269504f;
  float a21 = -expf(Alog[d*16+n0+1]) * 1.44269504f;
  float w0=cw[d*4], w1=cw[d*4+1], w2=cw[d*4+2], w3=cw[d*4+3], cbb=cbv[d];
  float dpv = Dv[d];
  float dw0=dtw[d*8+0], dw1=dtw[d*8+1], dw2=dtw[d*8+2], dw3=dtw[d*8+3];
  float dw4=dtw[d*8+4], dw5=dtw[d*8+5], dw6=dtw[d*8+6], dw7=dtw[d*8+7];
  float dtb_d = dtbv[d];
  float h0=0.f, h1=0.f, p1=0.f, p2=0.f, p3=0.f;
  long xi  = ((long)b*LL + (fwd ? 0 : LL-1))*256 + d;
  long ri  = ((long)s*LL)*8;
  long bi  = ((long)s*LL)*32 + n0;
  long yi  = ((long)s*LL)*256 + d;
  long xstep = fwd ? 256 : -256;
  for (int l=0; l<LL; ++l){
    float xl = bf2f(xm[xi]);
    float xc = w3*xl + w2*p1 + w1*p2 + w0*p3 + cbb;
    p3=p2; p2=p1; p1=xl;
    float u  = xc/(1.f + __expf(-xc));
    float4 r0 = *reinterpret_cast<const float4*>(dtr + ri);
    float4 r1 = *reinterpret_cast<const float4*>(dtr + ri + 4);
    float xacc = dtb_d;
    xacc = fmaf(r0.x,dw0, fmaf(r0.y,dw1, fmaf(r0.z,dw2, fmaf(r0.w,dw3, xacc))));
    xacc = fmaf(r1.x,dw4, fmaf(r1.y,dw5, fmaf(r1.z,dw6, fmaf(r1.w,dw7, xacc))));
    float dt = (xacc > 20.f) ? xacc : __logf(1.f + __expf(xacc));
    float dtu = dt*u;
    float b0 = bf2f(bc[bi]),    b1 = bf2f(bc[bi+1]);
    float c0 = bf2f(bc[bi+16]), c1 = bf2f(bc[bi+17]);
    float e0 = exp2f(dt*a20), e1 = exp2f(dt*a21);
    h0 = fmaf(e0, h0, dtu*b0);
    h1 = fmaf(e1, h1, dtu*b1);
    float yc = fmaf(h0, c0, h1*c1);
    yc += __shfl_xor(yc,1); yc += __shfl_xor(yc,2); yc += __shfl_xor(yc,4);
    if (np == 0){
      float zv = bf2f(zm[xi]);
      yb[yi] = f2bf((yc + u*dpv)*zv);
    }
    xi += xstep; ri += 8; bi += 32; yi += 256;
  }
}

// ======================= combine fwd/bwd (both already zm-gated) =======================
__global__ __launch_bounds__(256) void combine_kernel(
    const __hip_bfloat16* __restrict__ yb, __hip_bfloat16* __restrict__ ycomb,
    int tokens, int nb)
{
  long gid = (long)blockIdx.x*256 + threadIdx.x;
  long tok = gid >> 8;
  if (tok >= tokens) return;
  int c = gid & 255;
  long l = tok % LL, b = tok / LL;
  float vf = bf2f(yb[( b*LL + l)*256 + c]);
  float vb = bf2f(yb[((nb+b)*LL + (LL-1-l))*256 + c]);
  ycomb[gid] = f2bf(vf+vb);
}

// ======================= head: mean over tokens + linear =======================
__global__ __launch_bounds__(256) void head_kernel(
    const __hip_bfloat16* __restrict__ xb, const float* __restrict__ hw,
    const float* __restrict__ hb, float* __restrict__ out, int b0)
{
  __shared__ float partial[4][64];
  __shared__ float feat[64];
  int b = blockIdx.x;
  int d = threadIdx.x & 63, part = threadIdx.x >> 6;
  float acc = 0.f;
  for (int l = part; l < LL; l += 4) acc += bf2f(xb[((long)b*LL + l)*64 + d]);
  partial[part][d] = acc;
  __syncthreads();
  if (part == 0){
    float f = (partial[0][d]+partial[1][d]+partial[2][d]+partial[3][d]) * (1.f/3630.f);
    feat[d] = f;
    out[512 + (b0+b)*64 + d] = f;
  }
  __syncthreads();
  if (threadIdx.x < 16){
    float a2 = hb[threadIdx.x];
    for (int k=0; k<64; ++k) a2 += feat[k]*hw[threadIdx.x*64+k];
    out[(b0+b)*16 + threadIdx.x] = a2;
  }
}

// ======================= launch =======================
extern "C" void kernel_launch(void* const* d_in, const int* in_sizes, int n_in,
                              void* d_out, int out_size, void* d_ws, size_t ws_size,
                              hipStream_t stream)
{
  const float* x        = (const float*)d_in[0];
  const float* sconv_w  = (const float*)d_in[1];
  const float* bn1_g    = (const float*)d_in[2];
  const float* bn1_b    = (const float*)d_in[3];
  const float* bn1_m    = (const float*)d_in[4];
  const float* bn1_v    = (const float*)d_in[5];
  const float* tconv_w  = (const float*)d_in[6];
  const float* bn2_g    = (const float*)d_in[7];
  const float* bn2_b    = (const float*)d_in[8];
  const float* bn2_m    = (const float*)d_in[9];
  const float* bn2_v    = (const float*)d_in[10];
  const float* last_w   = (const float*)d_in[11];
  const float* ln1_g    = (const float*)d_in[12];
  const float* ln1_b    = (const float*)d_in[13];
  const float* in_proj_w= (const float*)d_in[14];
  const float* conv3d_w = (const float*)d_in[15];
  const float* conv3d_b = (const float*)d_in[16];
  const float* m_in_w   = (const float*)d_in[17];
  const float* m_conv_w = (const float*)d_in[18];
  const float* m_conv_b = (const float*)d_in[19];
  const float* m_xproj_w= (const float*)d_in[20];
  const float* m_dtproj_w=(const float*)d_in[21];
  const float* m_dtproj_b=(const float*)d_in[22];
  const float* m_Alog   = (const float*)d_in[23];
  const float* m_D      = (const float*)d_in[24];
  const float* m_out_w  = (const float*)d_in[25];
  const float* out_proj_w=(const float*)d_in[26];
  const float* ln2_g    = (const float*)d_in[27];
  const float* ln2_b    = (const float*)d_in[28];
  const float* fc1_w    = (const float*)d_in[29];
  const float* fc1_b    = (const float*)d_in[30];
  const float* fc2_w    = (const float*)d_in[31];
  const float* fc2_b    = (const float*)d_in[32];
  const float* head_w   = (const float*)d_in[33];
  const float* head_b   = (const float*)d_in[34];

  // pick largest chunk size (videos per pass) whose arena fits ws_size
  int nb = 1;
  for (int cand = 32; cand >= 1; cand >>= 1){
    size_t TPc = (((size_t)cand*LL + 63)/64)*64;
    size_t S2c = (size_t)2*cand*LL;
    size_t need = 1245184 + TPc*2048 + S2c*544;
    if (need <= ws_size){ nb = cand; break; }
  }
  const size_t TP  = (((size_t)nb*LL + 63)/64)*64;
  const size_t S2T = (size_t)2*nb*LL;
  const int tokens = nb*LL;

  char* ws = (char*)d_ws;
  __hip_bfloat16* wbf   = (__hip_bfloat16*)(ws);
  size_t o = 1245184;
  __hip_bfloat16* xb    = (__hip_bfloat16*)(ws + o); o += TP*128;
  __hip_bfloat16* hx    = (__hip_bfloat16*)(ws + o);
  __hip_bfloat16* bcb   = hx;                        o += TP*128;   // bc aliases hx
  __hip_bfloat16* xs    = (__hip_bfloat16*)(ws + o); o += TP*256;
  __hip_bfloat16* seq   = (__hip_bfloat16*)(ws + o); o += TP*256;
  __hip_bfloat16* ycomb = xs;                                       // xs+seq region
  __hip_bfloat16* zblk  = (__hip_bfloat16*)(ws + o); o += TP*256;
  __hip_bfloat16* xm    = (__hip_bfloat16*)(ws + o);
  __hip_bfloat16* yo    = xm;                        o += TP*512;   // yo aliases xm
  __hip_bfloat16* zm    = (__hip_bfloat16*)(ws + o);
  __hip_bfloat16* h2m   = zm;                        o += TP*512;   // h2m aliases zm
  float*          dtr   = (float*)(ws + o);          o += S2T*32;
  __hip_bfloat16* ybuf  = (__hip_bfloat16*)(ws + o);                // [S2T,256]
  float*          h1s   = (float*)(ws + o);                         // stem tmp aliases ybuf
  float*          h2s   = (float*)(ws + o + (size_t)nb*495616);

  convert_weights<<<2432, 256, 0, stream>>>(in_proj_w, m_in_w, m_out_w, out_proj_w, fc1_w, fc2_w, wbf);

  const int gM = (int)(TP/64);

  for (int b0 = 0; b0 < 32; b0 += nb){
    stem1_kernel<<<nb*484, 256, 0, stream>>>(x, sconv_w, bn1_g, bn1_b, bn1_m, bn1_v, h1s, nb, b0);
    stem2_kernel<<<(nb*116160+255)/256, 256, 0, stream>>>(h1s, tconv_w, bn2_g, bn2_b, bn2_m, bn2_v, h2s, nb);
    stem3_kernel<<<(tokens*64+255)/256, 256, 0, stream>>>(h2s, last_w, xb, tokens);

    for (int i = 0; i < 4; ++i){
      ln_kernel<<<(tokens+3)/4, 256, 0, stream>>>(xb, ln1_g + i*64, ln1_b + i*64, hx, tokens);
      gemm_bf16<0><<<dim3(gM,4), 256, 0, stream>>>(hx, wbf + i*16384, 64, 256, 128, tokens,
                                                   xs, zblk, nullptr, nullptr, nullptr);
      dwconv3d_kernel<<<(tokens*128+255)/256, 256, 0, stream>>>(xs, conv3d_w + i*3456, conv3d_b + i*128, seq, tokens);
      gemm_bf16<0><<<dim3(gM,8), 256, 0, stream>>>(seq, wbf + 65536 + i*65536, 128, 512, 256, tokens,
                                                   xm, zm, nullptr, nullptr, nullptr);
      mamba_pre_kernel<<<2*nb*363, 256, 0, stream>>>(xm, m_conv_w + i*1024, m_conv_b + i*256,
                                                     m_xproj_w + i*10240, bcb, dtr, nb);
      scan_kernel<<<16*nb, 256, 0, stream>>>(xm, dtr, bcb, zm, m_conv_w + i*1024, m_conv_b + i*256,
                                             m_dtproj_w + i*2048, m_dtproj_b + i*256,
                                             m_Alog + i*4096, m_D + i*256, ybuf, nb);
      combine_kernel<<<(tokens*256+255)/256, 256, 0, stream>>>(ybuf, ycomb, tokens, nb);
      gemm_bf16<4><<<dim3(gM,2), 256, 0, stream>>>(ycomb, wbf + 327680 + i*32768, 256, 128, 0, tokens,
                                                   yo, nullptr, nullptr, zblk, nullptr);
      gemm_bf16<3><<<dim3(gM,1), 256, 0, stream>>>(yo, wbf + 458752 + i*8192, 128, 64, 0, tokens,
                                                   nullptr, nullptr, nullptr, nullptr, xb);
      ln_kernel<<<(tokens+3)/4, 256, 0, stream>>>(xb, ln2_g + i*64, ln2_b + i*64, hx, tokens);
      gemm_bf16<2><<<dim3(gM,4), 256, 0, stream>>>(hx, wbf + 491520 + i*16384, 64, 256, 0, tokens,
                                                   h2m, nullptr, fc1_b + i*256, nullptr, nullptr);
      gemm_bf16<3><<<dim3(gM,1), 256, 0, stream>>>(h2m, wbf + 557056 + i*16384, 256, 64, 0, tokens,
                                                   nullptr, nullptr, fc2_b + i*64, nullptr, xb);
    }
    head_kernel<<<nb, 256, 0, stream>>>(xb, head_w, head_b, (float*)d_out, b0);
  }
}

// Round 3
// 11940.200 us; speedup vs baseline: 2.5115x; 2.5115x over previous
//
#include <hip/hip_runtime.h>
#include <hip/hip_bf16.h>
#include <hip/hip_fp16.h>

#define LL    3630
#define EPSV  1e-5f
#define NCH   30      // scan chunks
#define CLEN  121     // LL = NCH*CLEN

typedef short bf16x8 __attribute__((ext_vector_type(8)));
typedef float f32x4  __attribute__((ext_vector_type(4)));

__device__ __forceinline__ float bf2f(__hip_bfloat16 x){ return __bfloat162float(x); }
__device__ __forceinline__ __hip_bfloat16 f2bf(float x){ return __float2bfloat16(x); }
__device__ __forceinline__ float siluf(float x){ return x / (1.f + __expf(-x)); }

// ======================= weight f32 -> bf16 =======================
// 0..65535 in_proj | ..327679 m_in | ..458751 m_out | ..491519 out_proj |
// ..557055 fc1 | ..622591 fc2 | ..671743 xproj padded 4x[48][256] (rows40-47 = 0)
__global__ __launch_bounds__(256) void convert_weights(
    const float* __restrict__ s0, const float* __restrict__ s1,
    const float* __restrict__ s2, const float* __restrict__ s3,
    const float* __restrict__ s4, const float* __restrict__ s5,
    const float* __restrict__ s6,
    __hip_bfloat16* __restrict__ dst)
{
  int gid = blockIdx.x*256 + threadIdx.x;
  float v;
  if      (gid <  65536) v = s0[gid];
  else if (gid < 327680) v = s1[gid-65536];
  else if (gid < 458752) v = s2[gid-327680];
  else if (gid < 491520) v = s3[gid-458752];
  else if (gid < 557056) v = s4[gid-491520];
  else if (gid < 622592) v = s5[gid-557056];
  else if (gid < 671744){
    int rel = gid - 622592;
    int layer = rel / 12288;
    int rr  = (rel % 12288) / 256;
    int ccol= rel & 255;
    v = (rr < 40) ? s6[layer*10240 + rr*256 + ccol] : 0.f;
  }
  else return;
  dst[gid] = f2bf(v);
}

// ======================= stem =======================
__global__ __launch_bounds__(256) void stem1_kernel(
    const float* __restrict__ x, const float* __restrict__ w,
    const float* __restrict__ g, const float* __restrict__ bb,
    const float* __restrict__ mm, const float* __restrict__ vv,
    float* __restrict__ out, int nb, int b0)
{
  int idx = blockIdx.x*256 + threadIdx.x;
  if (idx >= nb*123904) return;
  int j = idx % 11;
  int i = (idx/11) % 11;
  int t = (idx/121) % 32;
  int c = (idx/(121*32)) % 32;
  int b = idx/(121*32*32);
  const float* xp = x + ((b0+b)*32 + t)*169;
  const float* wp = w + c*9;
  float acc = 0.f;
  #pragma unroll
  for (int di=0; di<3; ++di)
    #pragma unroll
    for (int dj=0; dj<3; ++dj)
      acc += xp[(i+di)*13 + (j+dj)] * wp[di*3+dj];
  float s = g[c]*rsqrtf(vv[c]+EPSV);
  acc = acc*s + (bb[c]-mm[c]*s);
  out[idx] = fmaxf(acc, 0.f);
}

__global__ __launch_bounds__(256) void stem2_kernel(
    const float* __restrict__ h1, const float* __restrict__ w,
    const float* __restrict__ g, const float* __restrict__ bb,
    const float* __restrict__ mm, const float* __restrict__ vv,
    float* __restrict__ out, int nb)
{
  int idx = blockIdx.x*256 + threadIdx.x;
  if (idx >= nb*116160) return;
  int ij = idx % 121;
  int t  = (idx/121) % 30;
  int c  = (idx/(121*30)) % 32;
  int b  = idx/(121*30*32);
  const float* hp = h1 + ((b*32+c)*32)*121 + ij;
  const float* wp = w + c*3;
  float acc = 0.f;
  #pragma unroll
  for (int k=0;k<3;++k) acc += hp[(t+k)*121] * wp[k];
  float s = g[c]*rsqrtf(vv[c]+EPSV);
  acc = acc*s + (bb[c]-mm[c]*s);
  out[idx] = fmaxf(acc, 0.f);
}

__global__ __launch_bounds__(256) void stem3_kernel(
    const float* __restrict__ h2, const float* __restrict__ w,
    __hip_bfloat16* __restrict__ xb, int tokens)
{
  int gid = blockIdx.x*256 + threadIdx.x;
  int cc = gid & 63;
  int tok = gid >> 6;
  if (tok >= tokens) return;
  int ij = tok % 121;
  int t  = (tok/121) % 30;
  int b  = tok/LL;
  const float* hp = h2 + ((long)b*32)*30*121 + t*121 + ij;
  const float* wp = w + cc*32;
  float acc = 0.f;
  #pragma unroll
  for (int ci=0; ci<32; ++ci) acc += hp[ci*3630] * wp[ci];
  xb[(long)tok*64+cc] = f2bf(acc);
}

// ======================= layernorm (dim 64), bf16 in/out =======================
__global__ __launch_bounds__(256) void ln_kernel(
    const __hip_bfloat16* __restrict__ xb, const float* __restrict__ g,
    const float* __restrict__ b2, __hip_bfloat16* __restrict__ out, int tokens)
{
  int wid = threadIdx.x >> 6, lane = threadIdx.x & 63;
  long tok = (long)blockIdx.x*4 + wid;
  if (tok >= tokens) return;
  float v = bf2f(xb[tok*64 + lane]);
  float s = v, q = v*v;
  #pragma unroll
  for (int m=1; m<64; m<<=1){ s += __shfl_xor(s,m); q += __shfl_xor(q,m); }
  float mean = s*(1.f/64.f);
  float var  = q*(1.f/64.f) - mean*mean;
  float o = (v-mean)*rsqrtf(var+EPSV)*g[lane] + b2[lane];
  out[tok*64+lane] = f2bf(o);
}

// ======================= bf16 MFMA GEMM: out[M,N] = A[M,K] @ W[N,K]^T =======================
template<int EPI>
__global__ __launch_bounds__(256) void gemm_bf16(
    const __hip_bfloat16* __restrict__ A, const __hip_bfloat16* __restrict__ W,
    int K, int N, int NH, int tokens,
    __hip_bfloat16* __restrict__ out1, __hip_bfloat16* __restrict__ out2,
    const float* __restrict__ bias, const __hip_bfloat16* __restrict__ gate,
    __hip_bfloat16* __restrict__ resid)
{
  int w   = threadIdx.x >> 6;
  int lane= threadIdx.x & 63;
  int r16 = lane & 15;
  int kg  = lane >> 4;          // 0..3
  long m0 = (long)blockIdx.x*64 + w*16;
  int  n0 = blockIdx.y*64;
  f32x4 acc[4] = { {0,0,0,0},{0,0,0,0},{0,0,0,0},{0,0,0,0} };
  for (int k0 = 0; k0 < K; k0 += 32){
    bf16x8 a = *reinterpret_cast<const bf16x8*>(A + (m0 + r16)*K + k0 + kg*8);
    #pragma unroll
    for (int f=0; f<4; ++f){
      bf16x8 b = *reinterpret_cast<const bf16x8*>(W + (long)(n0 + f*16 + r16)*K + k0 + kg*8);
      acc[f] = __builtin_amdgcn_mfma_f32_16x16x32_bf16(a, b, acc[f], 0, 0, 0);
    }
  }
  #pragma unroll
  for (int f=0; f<4; ++f){
    int col = n0 + f*16 + r16;
    #pragma unroll
    for (int r=0; r<4; ++r){
      long row = m0 + kg*4 + r;
      if (row >= tokens) continue;
      float v = acc[f][r];
      if (EPI == 0){
        if (col < NH) out1[row*NH + col] = f2bf(v);
        else          out2[row*NH + col - NH] = f2bf(siluf(v));
      } else if (EPI == 2){
        v += bias[col];
        v = 0.5f*v*(1.f + erff(v*0.70710678118f));
        out1[row*N + col] = f2bf(v);
      } else if (EPI == 3){
        if (bias) v += bias[col];
        resid[row*N + col] = f2bf(v + bf2f(resid[row*N + col]));
      } else {
        out1[row*N + col] = f2bf(v * bf2f(gate[row*N + col]));
      }
    }
  }
}

// ======================= depthwise conv3d 3x3x3 SAME + silu =======================
__global__ __launch_bounds__(256) void dwconv3d_kernel(
    const __hip_bfloat16* __restrict__ xs, const float* __restrict__ w,
    const float* __restrict__ bias, __hip_bfloat16* __restrict__ seq, int tokens)
{
  long gid = (long)blockIdx.x*256 + threadIdx.x;
  int c = gid & 127;
  long tok = gid >> 7;
  if (tok >= tokens) return;
  int j  = tok % 11;
  int i2 = (tok/11) % 11;
  int t  = (tok/121) % 30;
  long b = tok/LL;
  const float* wc = w + c*27;
  float acc = bias[c];
  #pragma unroll
  for (int dt=0; dt<3; ++dt){
    int tt = t+dt-1; if (tt<0 || tt>=30) continue;
    #pragma unroll
    for (int di=0; di<3; ++di){
      int ii = i2+di-1; if (ii<0 || ii>=11) continue;
      #pragma unroll
      for (int dj=0; dj<3; ++dj){
        int jj = j+dj-1; if (jj<0 || jj>=11) continue;
        long t2 = (b*30+tt)*121 + ii*11 + jj;
        acc += wc[dt*9+di*3+dj] * bf2f(xs[t2*128 + c]);
      }
    }
  }
  seq[tok*128 + c] = f2bf(siluf(acc));
}

// ======================= mamba_pre: conv1d+silu -> LDS, xproj via MFMA =======================
// grid = 2nb sequences * 57 chunks of 64 tokens; block 256 (4 waves)
__global__ __launch_bounds__(256) void mamba_pre_kernel(
    const __hip_bfloat16* __restrict__ xm,       // [nb, L, 256] fwd-order raw x
    const float* __restrict__ cw, const float* __restrict__ cbv,
    const __hip_bfloat16* __restrict__ xpw_bf,   // [48,256] zero-padded
    __hip_bfloat16* __restrict__ bc,             // [2nb, L, 32]
    float* __restrict__ dtr,                     // [2nb, L, 8]
    int nb)
{
  __shared__ __hip_bfloat16 xcs[64][264];   // +8 pad: 2-way banks only
  int s  = blockIdx.x / 57;
  int ch = blockIdx.x % 57;
  int p0 = ch*64;
  int b  = s % nb;
  bool fwd = s < nb;
  int d = threadIdx.x;
  const long basex = (long)b*LL*256 + d;
  float w0=cw[d*4], w1=cw[d*4+1], w2=cw[d*4+2], w3=cw[d*4+3], cb=cbv[d];
  float p1=0.f, p2=0.f, p3=0.f;
  if (p0-1 >= 0) p1 = bf2f(xm[basex + (long)(fwd ? p0-1 : LL-p0  )*256]);
  if (p0-2 >= 0) p2 = bf2f(xm[basex + (long)(fwd ? p0-2 : LL+1-p0)*256]);
  if (p0-3 >= 0) p3 = bf2f(xm[basex + (long)(fwd ? p0-3 : LL+2-p0)*256]);
  for (int t=0; t<64; ++t){
    int p = p0 + t;
    float xl = 0.f;
    if (p < LL) xl = bf2f(xm[basex + (long)(fwd ? p : LL-1-p)*256]);
    float xc = w3*xl + w2*p1 + w1*p2 + w0*p3 + cb;
    p3=p2; p2=p1; p1=xl;
    xcs[t][d] = f2bf(siluf(xc));
  }
  __syncthreads();
  int w = threadIdx.x >> 6, lane = threadIdx.x & 63;
  int r16 = lane & 15, kg = lane >> 4;
  int t0 = w*16;
  f32x4 acc[3] = { {0,0,0,0},{0,0,0,0},{0,0,0,0} };
  for (int k0=0; k0<256; k0+=32){
    bf16x8 a = *reinterpret_cast<const bf16x8*>(&xcs[t0+r16][k0+kg*8]);
    #pragma unroll
    for (int f=0; f<3; ++f){
      bf16x8 bb = *reinterpret_cast<const bf16x8*>(xpw_bf + (f*16+r16)*256 + k0 + kg*8);
      acc[f] = __builtin_amdgcn_mfma_f32_16x16x32_bf16(a, bb, acc[f], 0, 0, 0);
    }
  }
  long sLL = (long)s*LL;
  #pragma unroll
  for (int f=0; f<3; ++f){
    int col = f*16 + r16;
    #pragma unroll
    for (int r=0; r<4; ++r){
      int tl = t0 + kg*4 + r;
      int p = p0 + tl;
      if (p >= LL) continue;
      long tok = sLL + p;
      float v = acc[f][r];
      if (col < 8)       dtr[tok*8 + col] = v;
      else if (col < 40) bc[tok*32 + col-8] = f2bf(v);
    }
  }
}

// ======================= chunked selective scan =======================
// pass1: per-chunk scan from h=0 -> hfinal[s,ch,d,n] (f32) + sdt[s,ch,d]
// grid = 2nb*NCH*8; block 256 (4 waves); lane owns (d, n0..n0+1)
__global__ __launch_bounds__(256) void scan_p1(
    const __hip_bfloat16* __restrict__ xm,
    const float* __restrict__ dtr,
    const __hip_bfloat16* __restrict__ bc,
    const float* __restrict__ cw, const float* __restrict__ cbv,
    const float* __restrict__ dtw, const float* __restrict__ dtbv,
    const float* __restrict__ Alog,
    float* __restrict__ hfin, float* __restrict__ sdt,
    int nb)
{
  int wid = threadIdx.x >> 6, lane = threadIdx.x & 63;
  int dgrp = blockIdx.x & 7;
  int sc = blockIdx.x >> 3;            // s*NCH + ch
  int ch = sc % NCH, s = sc / NCH;
  int dl = lane >> 3, np = lane & 7;
  int d = dgrp*32 + wid*8 + dl;
  int b = s % nb;
  bool fwd = s < nb;
  int n0 = np*2;
  float a20 = -expf(Alog[d*16+n0  ]) * 1.44269504f;
  float a21 = -expf(Alog[d*16+n0+1]) * 1.44269504f;
  float w0=cw[d*4], w1=cw[d*4+1], w2=cw[d*4+2], w3=cw[d*4+3], cbb=cbv[d];
  float dw0=dtw[d*8+0], dw1=dtw[d*8+1], dw2=dtw[d*8+2], dw3=dtw[d*8+3];
  float dw4=dtw[d*8+4], dw5=dtw[d*8+5], dw6=dtw[d*8+6], dw7=dtw[d*8+7];
  float dtb_d = dtbv[d];
  int l0 = ch*CLEN;
  long basex = (long)b*LL*256 + d;
  float p1=0.f, p2=0.f, p3=0.f;
  if (l0 >= 1) p1 = bf2f(xm[basex + (long)(fwd ? l0-1 : LL-l0  )*256]);
  if (l0 >= 2) p2 = bf2f(xm[basex + (long)(fwd ? l0-2 : LL+1-l0)*256]);
  if (l0 >= 3) p3 = bf2f(xm[basex + (long)(fwd ? l0-3 : LL+2-l0)*256]);
  float h0=0.f, h1=0.f, sacc=0.f;
  long xi = basex + (long)(fwd ? l0 : LL-1-l0)*256;
  long ri = ((long)s*LL + l0)*8;
  long bi = ((long)s*LL + l0)*32 + n0;
  long xstep = fwd ? 256 : -256;
  for (int l=0; l<CLEN; ++l){
    float xl = bf2f(xm[xi]);
    float xc = w3*xl + w2*p1 + w1*p2 + w0*p3 + cbb;
    p3=p2; p2=p1; p1=xl;
    float u  = xc/(1.f + __expf(-xc));
    float4 r0 = *reinterpret_cast<const float4*>(dtr + ri);
    float4 r1 = *reinterpret_cast<const float4*>(dtr + ri + 4);
    float xacc = dtb_d;
    xacc = fmaf(r0.x,dw0, fmaf(r0.y,dw1, fmaf(r0.z,dw2, fmaf(r0.w,dw3, xacc))));
    xacc = fmaf(r1.x,dw4, fmaf(r1.y,dw5, fmaf(r1.z,dw6, fmaf(r1.w,dw7, xacc))));
    float dt = (xacc > 20.f) ? xacc : __logf(1.f + __expf(xacc));
    sacc += dt;
    float dtu = dt*u;
    float b0 = bf2f(bc[bi]),    b1 = bf2f(bc[bi+1]);
    float e0 = exp2f(dt*a20), e1 = exp2f(dt*a21);
    h0 = fmaf(e0, h0, dtu*b0);
    h1 = fmaf(e1, h1, dtu*b1);
    xi += xstep; ri += 8; bi += 32;
  }
  long hidx = ((long)sc*256 + d)*16 + n0;
  float2 hv; hv.x = h0; hv.y = h1;
  *reinterpret_cast<float2*>(hfin + hidx) = hv;
  if (np == 0) sdt[(long)sc*256 + d] = sacc;
}

// sequential chunk combine (in-place: hfin becomes hinit)
// grid = 2nb*16; block 256: d = dg*16 + tid>>4, n = tid&15
__global__ __launch_bounds__(256) void scan_comb(
    const float* __restrict__ Alog,
    float* __restrict__ hfin, const float* __restrict__ sdt)
{
  int s = blockIdx.x >> 4, dg = blockIdx.x & 15;
  int d = dg*16 + (threadIdx.x >> 4), n = threadIdx.x & 15;
  float a2 = -expf(Alog[d*16+n]) * 1.44269504f;
  float h = 0.f;
  for (int ch=0; ch<NCH; ++ch){
    long sc = (long)s*NCH + ch;
    long idx = (sc*256 + d)*16 + n;
    float hf = hfin[idx];
    float sd = sdt[sc*256 + d];
    hfin[idx] = h;
    h = exp2f(a2*sd)*h + hf;
  }
}

// pass2: rescan chunk from hinit, write gated y
__global__ __launch_bounds__(256) void scan_p2(
    const __hip_bfloat16* __restrict__ xm,
    const float* __restrict__ dtr,
    const __hip_bfloat16* __restrict__ bc,
    const __hip_bfloat16* __restrict__ zm,
    const float* __restrict__ cw, const float* __restrict__ cbv,
    const float* __restrict__ dtw, const float* __restrict__ dtbv,
    const float* __restrict__ Alog, const float* __restrict__ Dv,
    const float* __restrict__ hinit,
    __hip_bfloat16* __restrict__ yb,
    int nb)
{
  int wid = threadIdx.x >> 6, lane = threadIdx.x & 63;
  int dgrp = blockIdx.x & 7;
  int sc = blockIdx.x >> 3;
  int ch = sc % NCH, s = sc / NCH;
  int dl = lane >> 3, np = lane & 7;
  int d = dgrp*32 + wid*8 + dl;
  int b = s % nb;
  bool fwd = s < nb;
  int n0 = np*2;
  float a20 = -expf(Alog[d*16+n0  ]) * 1.44269504f;
  float a21 = -expf(Alog[d*16+n0+1]) * 1.44269504f;
  float w0=cw[d*4], w1=cw[d*4+1], w2=cw[d*4+2], w3=cw[d*4+3], cbb=cbv[d];
  float dw0=dtw[d*8+0], dw1=dtw[d*8+1], dw2=dtw[d*8+2], dw3=dtw[d*8+3];
  float dw4=dtw[d*8+4], dw5=dtw[d*8+5], dw6=dtw[d*8+6], dw7=dtw[d*8+7];
  float dtb_d = dtbv[d];
  float dpv = Dv[d];
  int l0 = ch*CLEN;
  long basex = (long)b*LL*256 + d;
  float p1=0.f, p2=0.f, p3=0.f;
  if (l0 >= 1) p1 = bf2f(xm[basex + (long)(fwd ? l0-1 : LL-l0  )*256]);
  if (l0 >= 2) p2 = bf2f(xm[basex + (long)(fwd ? l0-2 : LL+1-l0)*256]);
  if (l0 >= 3) p3 = bf2f(xm[basex + (long)(fwd ? l0-3 : LL+2-l0)*256]);
  long hidx = ((long)sc*256 + d)*16 + n0;
  float2 hv = *reinterpret_cast<const float2*>(hinit + hidx);
  float h0 = hv.x, h1 = hv.y;
  long xi = basex + (long)(fwd ? l0 : LL-1-l0)*256;
  long ri = ((long)s*LL + l0)*8;
  long bi = ((long)s*LL + l0)*32 + n0;
  long yi = ((long)s*LL + l0)*256 + d;
  long xstep = fwd ? 256 : -256;
  for (int l=0; l<CLEN; ++l){
    float xl = bf2f(xm[xi]);
    float xc = w3*xl + w2*p1 + w1*p2 + w0*p3 + cbb;
    p3=p2; p2=p1; p1=xl;
    float u  = xc/(1.f + __expf(-xc));
    float4 r0 = *reinterpret_cast<const float4*>(dtr + ri);
    float4 r1 = *reinterpret_cast<const float4*>(dtr + ri + 4);
    float xacc = dtb_d;
    xacc = fmaf(r0.x,dw0, fmaf(r0.y,dw1, fmaf(r0.z,dw2, fmaf(r0.w,dw3, xacc))));
    xacc = fmaf(r1.x,dw4, fmaf(r1.y,dw5, fmaf(r1.z,dw6, fmaf(r1.w,dw7, xacc))));
    float dt = (xacc > 20.f) ? xacc : __logf(1.f + __expf(xacc));
    float dtu = dt*u;
    float b0 = bf2f(bc[bi]),    b1 = bf2f(bc[bi+1]);
    float c0 = bf2f(bc[bi+16]), c1 = bf2f(bc[bi+17]);
    float e0 = exp2f(dt*a20), e1 = exp2f(dt*a21);
    h0 = fmaf(e0, h0, dtu*b0);
    h1 = fmaf(e1, h1, dtu*b1);
    float yc = fmaf(h0, c0, h1*c1);
    yc += __shfl_xor(yc,1); yc += __shfl_xor(yc,2); yc += __shfl_xor(yc,4);
    if (np == 0){
      float zv = bf2f(zm[xi]);
      yb[yi] = f2bf((yc + u*dpv)*zv);
    }
    xi += xstep; ri += 8; bi += 32; yi += 256;
  }
}

// ======================= combine fwd/bwd (both already zm-gated) =======================
__global__ __launch_bounds__(256) void combine_kernel(
    const __hip_bfloat16* __restrict__ yb, __hip_bfloat16* __restrict__ ycomb,
    int tokens, int nb)
{
  long gid = (long)blockIdx.x*256 + threadIdx.x;
  long tok = gid >> 8;
  if (tok >= tokens) return;
  int c = gid & 255;
  long l = tok % LL, b = tok / LL;
  float vf = bf2f(yb[( b*LL + l)*256 + c]);
  float vb = bf2f(yb[((nb+b)*LL + (LL-1-l))*256 + c]);
  ycomb[gid] = f2bf(vf+vb);
}

// ======================= head: mean over tokens + linear =======================
__global__ __launch_bounds__(256) void head_kernel(
    const __hip_bfloat16* __restrict__ xb, const float* __restrict__ hw,
    const float* __restrict__ hb, float* __restrict__ out, int b0)
{
  __shared__ float partial[4][64];
  __shared__ float feat[64];
  int b = blockIdx.x;
  int d = threadIdx.x & 63, part = threadIdx.x >> 6;
  float acc = 0.f;
  for (int l = part; l < LL; l += 4) acc += bf2f(xb[((long)b*LL + l)*64 + d]);
  partial[part][d] = acc;
  __syncthreads();
  if (part == 0){
    float f = (partial[0][d]+partial[1][d]+partial[2][d]+partial[3][d]) * (1.f/3630.f);
    feat[d] = f;
    out[512 + (b0+b)*64 + d] = f;
  }
  __syncthreads();
  if (threadIdx.x < 16){
    float a2 = hb[threadIdx.x];
    for (int k=0; k<64; ++k) a2 += feat[k]*hw[threadIdx.x*64+k];
    out[(b0+b)*16 + threadIdx.x] = a2;
  }
}

// ======================= launch =======================
extern "C" void kernel_launch(void* const* d_in, const int* in_sizes, int n_in,
                              void* d_out, int out_size, void* d_ws, size_t ws_size,
                              hipStream_t stream)
{
  const float* x        = (const float*)d_in[0];
  const float* sconv_w  = (const float*)d_in[1];
  const float* bn1_g    = (const float*)d_in[2];
  const float* bn1_b    = (const float*)d_in[3];
  const float* bn1_m    = (const float*)d_in[4];
  const float* bn1_v    = (const float*)d_in[5];
  const float* tconv_w  = (const float*)d_in[6];
  const float* bn2_g    = (const float*)d_in[7];
  const float* bn2_b    = (const float*)d_in[8];
  const float* bn2_m    = (const float*)d_in[9];
  const float* bn2_v    = (const float*)d_in[10];
  const float* last_w   = (const float*)d_in[11];
  const float* ln1_g    = (const float*)d_in[12];
  const float* ln1_b    = (const float*)d_in[13];
  const float* in_proj_w= (const float*)d_in[14];
  const float* conv3d_w = (const float*)d_in[15];
  const float* conv3d_b = (const float*)d_in[16];
  const float* m_in_w   = (const float*)d_in[17];
  const float* m_conv_w = (const float*)d_in[18];
  const float* m_conv_b = (const float*)d_in[19];
  const float* m_xproj_w= (const float*)d_in[20];
  const float* m_dtproj_w=(const float*)d_in[21];
  const float* m_dtproj_b=(const float*)d_in[22];
  const float* m_Alog   = (const float*)d_in[23];
  const float* m_D      = (const float*)d_in[24];
  const float* m_out_w  = (const float*)d_in[25];
  const float* out_proj_w=(const float*)d_in[26];
  const float* ln2_g    = (const float*)d_in[27];
  const float* ln2_b    = (const float*)d_in[28];
  const float* fc1_w    = (const float*)d_in[29];
  const float* fc1_b    = (const float*)d_in[30];
  const float* fc2_w    = (const float*)d_in[31];
  const float* fc2_b    = (const float*)d_in[32];
  const float* head_w   = (const float*)d_in[33];
  const float* head_b   = (const float*)d_in[34];

  const size_t WB = 1345536;   // bf16 weight arena bytes (671744*2, 64-aligned)
  // pick largest chunk size (videos per pass) whose arena fits ws_size
  int nb = 1;
  for (int cand = 32; cand >= 1; cand >>= 1){
    size_t TPc = (((size_t)cand*LL + 63)/64)*64;
    size_t S2c = (size_t)2*cand*LL;
    size_t need = WB + TPc*2048 + S2c*544;
    if (need <= ws_size){ nb = cand; break; }
  }
  const size_t TP  = (((size_t)nb*LL + 63)/64)*64;
  const int S2  = 2*nb;
  const int tokens = nb*LL;

  char* ws = (char*)d_ws;
  __hip_bfloat16* wbf   = (__hip_bfloat16*)(ws);
  size_t o = WB;
  __hip_bfloat16* xb    = (__hip_bfloat16*)(ws + o); o += TP*128;
  __hip_bfloat16* hx    = (__hip_bfloat16*)(ws + o);
  __hip_bfloat16* bcb   = hx;                        o += TP*128;   // bc aliases hx
  __hip_bfloat16* xs    = (__hip_bfloat16*)(ws + o); o += TP*256;
  __hip_bfloat16* seq   = (__hip_bfloat16*)(ws + o); o += TP*256;
  __hip_bfloat16* ycomb = xs;                                       // xs+seq region
  float*          hfin  = (float*)xs;                               // [S2*NCH*256*16] aliases xs+seq
  __hip_bfloat16* zblk  = (__hip_bfloat16*)(ws + o); o += TP*256;
  __hip_bfloat16* xm    = (__hip_bfloat16*)(ws + o);
  __hip_bfloat16* yo    = xm;                        o += TP*512;   // yo aliases xm
  __hip_bfloat16* zm    = (__hip_bfloat16*)(ws + o);
  __hip_bfloat16* h2m   = zm;                        o += TP*512;   // h2m aliases zm
  float*          dtr   = (float*)(ws + o);          o += (size_t)S2*LL*32;
  __hip_bfloat16* ybuf  = (__hip_bfloat16*)(ws + o);                // [S2*LL,256]
  float*          h1s   = (float*)(ws + o);                         // stem tmp aliases ybuf
  float*          h2s   = (float*)(ws + o + (size_t)nb*495616);
  float*          sdtb  = hfin + (size_t)S2*NCH*4096;               // [S2*NCH*256]

  convert_weights<<<2624, 256, 0, stream>>>(in_proj_w, m_in_w, m_out_w, out_proj_w,
                                            fc1_w, fc2_w, m_xproj_w, wbf);

  const int gM = (int)(TP/64);

  for (int b0 = 0; b0 < 32; b0 += nb){
    stem1_kernel<<<nb*484, 256, 0, stream>>>(x, sconv_w, bn1_g, bn1_b, bn1_m, bn1_v, h1s, nb, b0);
    stem2_kernel<<<(nb*116160+255)/256, 256, 0, stream>>>(h1s, tconv_w, bn2_g, bn2_b, bn2_m, bn2_v, h2s, nb);
    stem3_kernel<<<(tokens*64+255)/256, 256, 0, stream>>>(h2s, last_w, xb, tokens);

    for (int i = 0; i < 4; ++i){
      ln_kernel<<<(tokens+3)/4, 256, 0, stream>>>(xb, ln1_g + i*64, ln1_b + i*64, hx, tokens);
      gemm_bf16<0><<<dim3(gM,4), 256, 0, stream>>>(hx, wbf + i*16384, 64, 256, 128, tokens,
                                                   xs, zblk, nullptr, nullptr, nullptr);
      dwconv3d_kernel<<<(tokens*128+255)/256, 256, 0, stream>>>(xs, conv3d_w + i*3456, conv3d_b + i*128, seq, tokens);
      gemm_bf16<0><<<dim3(gM,8), 256, 0, stream>>>(seq, wbf + 65536 + i*65536, 128, 512, 256, tokens,
                                                   xm, zm, nullptr, nullptr, nullptr);
      mamba_pre_kernel<<<S2*57, 256, 0, stream>>>(xm, m_conv_w + i*1024, m_conv_b + i*256,
                                                  wbf + 622592 + i*12288, bcb, dtr, nb);
      scan_p1<<<S2*NCH*8, 256, 0, stream>>>(xm, dtr, bcb, m_conv_w + i*1024, m_conv_b + i*256,
                                            m_dtproj_w + i*2048, m_dtproj_b + i*256,
                                            m_Alog + i*4096, hfin, sdtb, nb);
      scan_comb<<<S2*16, 256, 0, stream>>>(m_Alog + i*4096, hfin, sdtb);
      scan_p2<<<S2*NCH*8, 256, 0, stream>>>(xm, dtr, bcb, zm, m_conv_w + i*1024, m_conv_b + i*256,
                                            m_dtproj_w + i*2048, m_dtproj_b + i*256,
                                            m_Alog + i*4096, m_D + i*256, hfin, ybuf, nb);
      combine_kernel<<<(tokens*256+255)/256, 256, 0, stream>>>(ybuf, ycomb, tokens, nb);
      gemm_bf16<4><<<dim3(gM,2), 256, 0, stream>>>(ycomb, wbf + 327680 + i*32768, 256, 128, 0, tokens,
                                                   yo, nullptr, nullptr, zblk, nullptr);
      gemm_bf16<3><<<dim3(gM,1), 256, 0, stream>>>(yo, wbf + 458752 + i*8192, 128, 64, 0, tokens,
                                                   nullptr, nullptr, nullptr, nullptr, xb);
      ln_kernel<<<(tokens+3)/4, 256, 0, stream>>>(xb, ln2_g + i*64, ln2_b + i*64, hx, tokens);
      gemm_bf16<2><<<dim3(gM,4), 256, 0, stream>>>(hx, wbf + 491520 + i*16384, 64, 256, 0, tokens,
                                                   h2m, nullptr, fc1_b + i*256, nullptr, nullptr);
      gemm_bf16<3><<<dim3(gM,1), 256, 0, stream>>>(h2m, wbf + 557056 + i*16384, 256, 64, 0, tokens,
                                                   nullptr, nullptr, fc2_b + i*64, nullptr, xb);
    }
    head_kernel<<<nb, 256, 0, stream>>>(xb, head_w, head_b, (float*)d_out, b0);
  }
}

// Round 4
// 7841.050 us; speedup vs baseline: 3.8245x; 1.5228x over previous
//
#include <hip/hip_runtime.h>
#include <hip/hip_bf16.h>
#include <hip/hip_fp16.h>

#define LL    3630
#define EPSV  1e-5f
#define NCH   33      // scan chunks
#define CLEN  110     // LL = NCH*CLEN

typedef short bf16x8 __attribute__((ext_vector_type(8)));
typedef float f32x4  __attribute__((ext_vector_type(4)));

__device__ __forceinline__ float bf2f(__hip_bfloat16 x){ return __bfloat162float(x); }
__device__ __forceinline__ __hip_bfloat16 f2bf(float x){ return __float2bfloat16(x); }
__device__ __forceinline__ float siluf(float x){ return x / (1.f + __expf(-x)); }

// ======================= weight f32 -> bf16 =======================
// 0..65535 in_proj | ..327679 m_in | ..458751 m_out | ..491519 out_proj |
// ..557055 fc1 | ..622591 fc2 | ..671743 xproj padded 4x[48][256] (rows40-47 = 0)
__global__ __launch_bounds__(256) void convert_weights(
    const float* __restrict__ s0, const float* __restrict__ s1,
    const float* __restrict__ s2, const float* __restrict__ s3,
    const float* __restrict__ s4, const float* __restrict__ s5,
    const float* __restrict__ s6,
    __hip_bfloat16* __restrict__ dst)
{
  int gid = blockIdx.x*256 + threadIdx.x;
  float v;
  if      (gid <  65536) v = s0[gid];
  else if (gid < 327680) v = s1[gid-65536];
  else if (gid < 458752) v = s2[gid-327680];
  else if (gid < 491520) v = s3[gid-458752];
  else if (gid < 557056) v = s4[gid-491520];
  else if (gid < 622592) v = s5[gid-557056];
  else if (gid < 671744){
    int rel = gid - 622592;
    int layer = rel / 12288;
    int rr  = (rel % 12288) / 256;
    int ccol= rel & 255;
    v = (rr < 40) ? s6[layer*10240 + rr*256 + ccol] : 0.f;
  }
  else return;
  dst[gid] = f2bf(v);
}

// ======================= stem =======================
__global__ __launch_bounds__(256) void stem1_kernel(
    const float* __restrict__ x, const float* __restrict__ w,
    const float* __restrict__ g, const float* __restrict__ bb,
    const float* __restrict__ mm, const float* __restrict__ vv,
    float* __restrict__ out, int nb, int b0)
{
  int idx = blockIdx.x*256 + threadIdx.x;
  if (idx >= nb*123904) return;
  int j = idx % 11;
  int i = (idx/11) % 11;
  int t = (idx/121) % 32;
  int c = (idx/(121*32)) % 32;
  int b = idx/(121*32*32);
  const float* xp = x + ((b0+b)*32 + t)*169;
  const float* wp = w + c*9;
  float acc = 0.f;
  #pragma unroll
  for (int di=0; di<3; ++di)
    #pragma unroll
    for (int dj=0; dj<3; ++dj)
      acc += xp[(i+di)*13 + (j+dj)] * wp[di*3+dj];
  float s = g[c]*rsqrtf(vv[c]+EPSV);
  acc = acc*s + (bb[c]-mm[c]*s);
  out[idx] = fmaxf(acc, 0.f);
}

__global__ __launch_bounds__(256) void stem2_kernel(
    const float* __restrict__ h1, const float* __restrict__ w,
    const float* __restrict__ g, const float* __restrict__ bb,
    const float* __restrict__ mm, const float* __restrict__ vv,
    float* __restrict__ out, int nb)
{
  int idx = blockIdx.x*256 + threadIdx.x;
  if (idx >= nb*116160) return;
  int ij = idx % 121;
  int t  = (idx/121) % 30;
  int c  = (idx/(121*30)) % 32;
  int b  = idx/(121*30*32);
  const float* hp = h1 + ((b*32+c)*32)*121 + ij;
  const float* wp = w + c*3;
  float acc = 0.f;
  #pragma unroll
  for (int k=0;k<3;++k) acc += hp[(t+k)*121] * wp[k];
  float s = g[c]*rsqrtf(vv[c]+EPSV);
  acc = acc*s + (bb[c]-mm[c]*s);
  out[idx] = fmaxf(acc, 0.f);
}

__global__ __launch_bounds__(256) void stem3_kernel(
    const float* __restrict__ h2, const float* __restrict__ w,
    __hip_bfloat16* __restrict__ xb, int tokens)
{
  int gid = blockIdx.x*256 + threadIdx.x;
  int cc = gid & 63;
  int tok = gid >> 6;
  if (tok >= tokens) return;
  int ij = tok % 121;
  int t  = (tok/121) % 30;
  int b  = tok/LL;
  const float* hp = h2 + ((long)b*32)*30*121 + t*121 + ij;
  const float* wp = w + cc*32;
  float acc = 0.f;
  #pragma unroll
  for (int ci=0; ci<32; ++ci) acc += hp[ci*3630] * wp[ci];
  xb[(long)tok*64+cc] = f2bf(acc);
}

// ======================= layernorm (dim 64), bf16 in/out =======================
__global__ __launch_bounds__(256) void ln_kernel(
    const __hip_bfloat16* __restrict__ xb, const float* __restrict__ g,
    const float* __restrict__ b2, __hip_bfloat16* __restrict__ out, int tokens)
{
  int wid = threadIdx.x >> 6, lane = threadIdx.x & 63;
  long tok = (long)blockIdx.x*4 + wid;
  if (tok >= tokens) return;
  float v = bf2f(xb[tok*64 + lane]);
  float s = v, q = v*v;
  #pragma unroll
  for (int m=1; m<64; m<<=1){ s += __shfl_xor(s,m); q += __shfl_xor(q,m); }
  float mean = s*(1.f/64.f);
  float var  = q*(1.f/64.f) - mean*mean;
  float o = (v-mean)*rsqrtf(var+EPSV)*g[lane] + b2[lane];
  out[tok*64+lane] = f2bf(o);
}

// ======================= bf16 MFMA GEMM: out[M,N] = A[M,K] @ W[N,K]^T =======================
template<int EPI>
__global__ __launch_bounds__(256) void gemm_bf16(
    const __hip_bfloat16* __restrict__ A, const __hip_bfloat16* __restrict__ W,
    int K, int N, int NH, int tokens,
    __hip_bfloat16* __restrict__ out1, __hip_bfloat16* __restrict__ out2,
    const float* __restrict__ bias, const __hip_bfloat16* __restrict__ gate,
    __hip_bfloat16* __restrict__ resid)
{
  int w   = threadIdx.x >> 6;
  int lane= threadIdx.x & 63;
  int r16 = lane & 15;
  int kg  = lane >> 4;          // 0..3
  long m0 = (long)blockIdx.x*64 + w*16;
  int  n0 = blockIdx.y*64;
  f32x4 acc[4] = { {0,0,0,0},{0,0,0,0},{0,0,0,0},{0,0,0,0} };
  for (int k0 = 0; k0 < K; k0 += 32){
    bf16x8 a = *reinterpret_cast<const bf16x8*>(A + (m0 + r16)*K + k0 + kg*8);
    #pragma unroll
    for (int f=0; f<4; ++f){
      bf16x8 b = *reinterpret_cast<const bf16x8*>(W + (long)(n0 + f*16 + r16)*K + k0 + kg*8);
      acc[f] = __builtin_amdgcn_mfma_f32_16x16x32_bf16(a, b, acc[f], 0, 0, 0);
    }
  }
  #pragma unroll
  for (int f=0; f<4; ++f){
    int col = n0 + f*16 + r16;
    #pragma unroll
    for (int r=0; r<4; ++r){
      long row = m0 + kg*4 + r;
      if (row >= tokens) continue;
      float v = acc[f][r];
      if (EPI == 0){
        if (col < NH) out1[row*NH + col] = f2bf(v);
        else          out2[row*NH + col - NH] = f2bf(siluf(v));
      } else if (EPI == 2){
        v += bias[col];
        v = 0.5f*v*(1.f + erff(v*0.70710678118f));
        out1[row*N + col] = f2bf(v);
      } else if (EPI == 3){
        if (bias) v += bias[col];
        resid[row*N + col] = f2bf(v + bf2f(resid[row*N + col]));
      } else {
        out1[row*N + col] = f2bf(v * bf2f(gate[row*N + col]));
      }
    }
  }
}

// ======================= depthwise conv3d 3x3x3 SAME + silu =======================
__global__ __launch_bounds__(256) void dwconv3d_kernel(
    const __hip_bfloat16* __restrict__ xs, const float* __restrict__ w,
    const float* __restrict__ bias, __hip_bfloat16* __restrict__ seq, int tokens)
{
  long gid = (long)blockIdx.x*256 + threadIdx.x;
  int c = gid & 127;
  long tok = gid >> 7;
  if (tok >= tokens) return;
  int j  = tok % 11;
  int i2 = (tok/11) % 11;
  int t  = (tok/121) % 30;
  long b = tok/LL;
  const float* wc = w + c*27;
  float acc = bias[c];
  #pragma unroll
  for (int dt=0; dt<3; ++dt){
    int tt = t+dt-1; if (tt<0 || tt>=30) continue;
    #pragma unroll
    for (int di=0; di<3; ++di){
      int ii = i2+di-1; if (ii<0 || ii>=11) continue;
      #pragma unroll
      for (int dj=0; dj<3; ++dj){
        int jj = j+dj-1; if (jj<0 || jj>=11) continue;
        long t2 = (b*30+tt)*121 + ii*11 + jj;
        acc += wc[dt*9+di*3+dj] * bf2f(xs[t2*128 + c]);
      }
    }
  }
  seq[tok*128 + c] = f2bf(siluf(acc));
}

// ======================= mamba_pre: conv1d+silu -> LDS + u out, xproj via MFMA =======================
// grid = 2nb sequences * 57 chunks of 64 tokens; block 256 (4 waves)
// outputs: ub [2nb,L,256] bf16 (u = silu(conv1d(x)));  pre [2nb,L,40] f32 (dt-rank 8 | B 16 | C 16)
__global__ __launch_bounds__(256) void mamba_pre_kernel(
    const __hip_bfloat16* __restrict__ xm,       // [nb, L, 256] fwd-order raw x
    const float* __restrict__ cw, const float* __restrict__ cbv,
    const __hip_bfloat16* __restrict__ xpw_bf,   // [48,256] zero-padded
    __hip_bfloat16* __restrict__ ub,
    float* __restrict__ pre,
    int nb)
{
  __shared__ __hip_bfloat16 xcs[64][264];   // +8 pad
  int s  = blockIdx.x / 57;
  int ch = blockIdx.x % 57;
  int p0 = ch*64;
  int b  = s % nb;
  bool fwd = s < nb;
  int d = threadIdx.x;
  const long basex = (long)b*LL*256 + d;
  const long sLL = (long)s*LL;
  float w0=cw[d*4], w1=cw[d*4+1], w2=cw[d*4+2], w3=cw[d*4+3], cb=cbv[d];
  float p1=0.f, p2=0.f, p3=0.f;
  if (p0-1 >= 0) p1 = bf2f(xm[basex + (long)(fwd ? p0-1 : LL-p0  )*256]);
  if (p0-2 >= 0) p2 = bf2f(xm[basex + (long)(fwd ? p0-2 : LL+1-p0)*256]);
  if (p0-3 >= 0) p3 = bf2f(xm[basex + (long)(fwd ? p0-3 : LL+2-p0)*256]);
  for (int t=0; t<64; ++t){
    int p = p0 + t;
    float xl = 0.f;
    if (p < LL) xl = bf2f(xm[basex + (long)(fwd ? p : LL-1-p)*256]);
    float xc = w3*xl + w2*p1 + w1*p2 + w0*p3 + cb;
    p3=p2; p2=p1; p1=xl;
    __hip_bfloat16 uv = f2bf(siluf(xc));
    xcs[t][d] = uv;
    if (p < LL) ub[(sLL + p)*256 + d] = uv;
  }
  __syncthreads();
  int w = threadIdx.x >> 6, lane = threadIdx.x & 63;
  int r16 = lane & 15, kg = lane >> 4;
  int t0 = w*16;
  f32x4 acc[3] = { {0,0,0,0},{0,0,0,0},{0,0,0,0} };
  for (int k0=0; k0<256; k0+=32){
    bf16x8 a = *reinterpret_cast<const bf16x8*>(&xcs[t0+r16][k0+kg*8]);
    #pragma unroll
    for (int f=0; f<3; ++f){
      bf16x8 bb = *reinterpret_cast<const bf16x8*>(xpw_bf + (f*16+r16)*256 + k0 + kg*8);
      acc[f] = __builtin_amdgcn_mfma_f32_16x16x32_bf16(a, bb, acc[f], 0, 0, 0);
    }
  }
  #pragma unroll
  for (int f=0; f<3; ++f){
    int col = f*16 + r16;
    #pragma unroll
    for (int r=0; r<4; ++r){
      int tl = t0 + kg*4 + r;
      int p = p0 + tl;
      if (p >= LL) continue;
      if (col < 40) pre[(sLL + p)*40 + col] = acc[f][r];
    }
  }
}

// ======================= chunked selective scan, lane = d =======================
// pass1: per-chunk scan from h=0 -> hfin[sc][d][16] f32 + sdt[sc][d]
// grid = 2nb*NCH blocks; block 256 threads (thread = d)
__global__ __launch_bounds__(256) void scan_p1(
    const __hip_bfloat16* __restrict__ ub,   // [2nb,L,256]
    const float* __restrict__ pre,           // [2nb,L,40]
    const float* __restrict__ dtw, const float* __restrict__ dtbv,
    const float* __restrict__ Alog,
    float* __restrict__ hfin, float* __restrict__ sdt)
{
  int d = threadIdx.x;
  int sc = blockIdx.x;
  int ch = sc % NCH, s = sc / NCH;
  float a2[16];
  #pragma unroll
  for (int n=0;n<16;++n) a2[n] = -__expf(Alog[d*16+n]) * 1.44269504f;
  float dw[8];
  #pragma unroll
  for (int r=0;r<8;++r) dw[r] = dtw[d*8+r];
  float dtb_d = dtbv[d];
  float h[16];
  #pragma unroll
  for (int n=0;n<16;++n) h[n] = 0.f;
  float sacc = 0.f;
  long tok0 = (long)s*LL + ch*CLEN;
  long ui = tok0*256 + d;
  long pi = tok0*40;
  for (int l=0; l<CLEN; ++l){
    float u = bf2f(ub[ui]);
    float4 r0 = *reinterpret_cast<const float4*>(pre+pi);
    float4 r1 = *reinterpret_cast<const float4*>(pre+pi+4);
    float xacc = dtb_d;
    xacc = fmaf(r0.x,dw[0],fmaf(r0.y,dw[1],fmaf(r0.z,dw[2],fmaf(r0.w,dw[3],xacc))));
    xacc = fmaf(r1.x,dw[4],fmaf(r1.y,dw[5],fmaf(r1.z,dw[6],fmaf(r1.w,dw[7],xacc))));
    float dt = (xacc > 20.f) ? xacc : __logf(1.f + __expf(xacc));
    sacc += dt;
    float dtu = dt*u;
    float4 B0 = *reinterpret_cast<const float4*>(pre+pi+8);
    float4 B1 = *reinterpret_cast<const float4*>(pre+pi+12);
    float4 B2 = *reinterpret_cast<const float4*>(pre+pi+16);
    float4 B3 = *reinterpret_cast<const float4*>(pre+pi+20);
    float Bv[16];
    Bv[0]=B0.x; Bv[1]=B0.y; Bv[2]=B0.z; Bv[3]=B0.w;
    Bv[4]=B1.x; Bv[5]=B1.y; Bv[6]=B1.z; Bv[7]=B1.w;
    Bv[8]=B2.x; Bv[9]=B2.y; Bv[10]=B2.z; Bv[11]=B2.w;
    Bv[12]=B3.x; Bv[13]=B3.y; Bv[14]=B3.z; Bv[15]=B3.w;
    #pragma unroll
    for (int n=0;n<16;++n){
      float e = exp2f(dt*a2[n]);
      h[n] = fmaf(e, h[n], dtu*Bv[n]);
    }
    ui += 256; pi += 40;
  }
  long hbase = ((long)sc*256 + d)*16;
  #pragma unroll
  for (int n=0;n<16;++n) hfin[hbase+n] = h[n];
  sdt[(long)sc*256 + d] = sacc;
}

// sequential chunk combine (in-place: hfin becomes hinit)
// grid = 2nb*16; block 256: d = dg*16 + tid>>4, n = tid&15
__global__ __launch_bounds__(256) void scan_comb(
    const float* __restrict__ Alog,
    float* __restrict__ hfin, const float* __restrict__ sdt)
{
  int s = blockIdx.x >> 4, dg = blockIdx.x & 15;
  int d = dg*16 + (threadIdx.x >> 4), n = threadIdx.x & 15;
  float a2 = -__expf(Alog[d*16+n]) * 1.44269504f;
  float h = 0.f;
  for (int ch=0; ch<NCH; ++ch){
    long sc = (long)s*NCH + ch;
    long idx = (sc*256 + d)*16 + n;
    float hf = hfin[idx];
    float sd = sdt[sc*256 + d];
    hfin[idx] = h;
    h = exp2f(a2*sd)*h + hf;
  }
}

// pass2: rescan chunk from hinit; y written over ub in-place (read-then-write same lane slot)
__global__ __launch_bounds__(256) void scan_p2(
    __hip_bfloat16* __restrict__ ub,         // [2nb,L,256] in: u, out: gated y
    const float* __restrict__ pre,
    const __hip_bfloat16* __restrict__ zm,   // [nb,L,256] silu'd
    const float* __restrict__ dtw, const float* __restrict__ dtbv,
    const float* __restrict__ Alog, const float* __restrict__ Dv,
    const float* __restrict__ hinit,
    int nb)
{
  int d = threadIdx.x;
  int sc = blockIdx.x;
  int ch = sc % NCH, s = sc / NCH;
  int b = s % nb;
  bool fwd = s < nb;
  float a2[16];
  #pragma unroll
  for (int n=0;n<16;++n) a2[n] = -__expf(Alog[d*16+n]) * 1.44269504f;
  float dw[8];
  #pragma unroll
  for (int r=0;r<8;++r) dw[r] = dtw[d*8+r];
  float dtb_d = dtbv[d];
  float dpv = Dv[d];
  float h[16];
  long hbase = ((long)sc*256 + d)*16;
  #pragma unroll
  for (int n=0;n<16;++n) h[n] = hinit[hbase+n];
  int l0 = ch*CLEN;
  long tok0 = (long)s*LL + l0;
  long ui = tok0*256 + d;
  long pi = tok0*40;
  long zi = ((long)b*LL + (fwd ? l0 : LL-1-l0))*256 + d;
  long zstep = fwd ? 256 : -256;
  for (int l=0; l<CLEN; ++l){
    float u = bf2f(ub[ui]);
    float4 r0 = *reinterpret_cast<const float4*>(pre+pi);
    float4 r1 = *reinterpret_cast<const float4*>(pre+pi+4);
    float xacc = dtb_d;
    xacc = fmaf(r0.x,dw[0],fmaf(r0.y,dw[1],fmaf(r0.z,dw[2],fmaf(r0.w,dw[3],xacc))));
    xacc = fmaf(r1.x,dw[4],fmaf(r1.y,dw[5],fmaf(r1.z,dw[6],fmaf(r1.w,dw[7],xacc))));
    float dt = (xacc > 20.f) ? xacc : __logf(1.f + __expf(xacc));
    float dtu = dt*u;
    float4 B0 = *reinterpret_cast<const float4*>(pre+pi+8);
    float4 B1 = *reinterpret_cast<const float4*>(pre+pi+12);
    float4 B2 = *reinterpret_cast<const float4*>(pre+pi+16);
    float4 B3 = *reinterpret_cast<const float4*>(pre+pi+20);
    float4 C0 = *reinterpret_cast<const float4*>(pre+pi+24);
    float4 C1 = *reinterpret_cast<const float4*>(pre+pi+28);
    float4 C2 = *reinterpret_cast<const float4*>(pre+pi+32);
    float4 C3 = *reinterpret_cast<const float4*>(pre+pi+36);
    float Bv[16], Cv[16];
    Bv[0]=B0.x; Bv[1]=B0.y; Bv[2]=B0.z; Bv[3]=B0.w;
    Bv[4]=B1.x; Bv[5]=B1.y; Bv[6]=B1.z; Bv[7]=B1.w;
    Bv[8]=B2.x; Bv[9]=B2.y; Bv[10]=B2.z; Bv[11]=B2.w;
    Bv[12]=B3.x; Bv[13]=B3.y; Bv[14]=B3.z; Bv[15]=B3.w;
    Cv[0]=C0.x; Cv[1]=C0.y; Cv[2]=C0.z; Cv[3]=C0.w;
    Cv[4]=C1.x; Cv[5]=C1.y; Cv[6]=C1.z; Cv[7]=C1.w;
    Cv[8]=C2.x; Cv[9]=C2.y; Cv[10]=C2.z; Cv[11]=C2.w;
    Cv[12]=C3.x; Cv[13]=C3.y; Cv[14]=C3.z; Cv[15]=C3.w;
    float y = 0.f;
    #pragma unroll
    for (int n=0;n<16;++n){
      float e = exp2f(dt*a2[n]);
      h[n] = fmaf(e, h[n], dtu*Bv[n]);
      y = fmaf(h[n], Cv[n], y);
    }
    float zv = bf2f(zm[zi]);
    ub[ui] = f2bf((y + u*dpv)*zv);
    ui += 256; pi += 40; zi += zstep;
  }
}

// ======================= combine fwd/bwd (both already zm-gated) =======================
__global__ __launch_bounds__(256) void combine_kernel(
    const __hip_bfloat16* __restrict__ yb, __hip_bfloat16* __restrict__ ycomb,
    int tokens, int nb)
{
  long gid = (long)blockIdx.x*256 + threadIdx.x;
  long tok = gid >> 8;
  if (tok >= tokens) return;
  int c = gid & 255;
  long l = tok % LL, b = tok / LL;
  float vf = bf2f(yb[( b*LL + l)*256 + c]);
  float vb = bf2f(yb[((nb+b)*LL + (LL-1-l))*256 + c]);
  ycomb[gid] = f2bf(vf+vb);
}

// ======================= head: mean over tokens + linear =======================
__global__ __launch_bounds__(256) void head_kernel(
    const __hip_bfloat16* __restrict__ xb, const float* __restrict__ hw,
    const float* __restrict__ hb, float* __restrict__ out, int b0)
{
  __shared__ float partial[4][64];
  __shared__ float feat[64];
  int b = blockIdx.x;
  int d = threadIdx.x & 63, part = threadIdx.x >> 6;
  float acc = 0.f;
  for (int l = part; l < LL; l += 4) acc += bf2f(xb[((long)b*LL + l)*64 + d]);
  partial[part][d] = acc;
  __syncthreads();
  if (part == 0){
    float f = (partial[0][d]+partial[1][d]+partial[2][d]+partial[3][d]) * (1.f/3630.f);
    feat[d] = f;
    out[512 + (b0+b)*64 + d] = f;
  }
  __syncthreads();
  if (threadIdx.x < 16){
    float a2 = hb[threadIdx.x];
    for (int k=0; k<64; ++k) a2 += feat[k]*hw[threadIdx.x*64+k];
    out[(b0+b)*16 + threadIdx.x] = a2;
  }
}

// ======================= launch =======================
extern "C" void kernel_launch(void* const* d_in, const int* in_sizes, int n_in,
                              void* d_out, int out_size, void* d_ws, size_t ws_size,
                              hipStream_t stream)
{
  const float* x        = (const float*)d_in[0];
  const float* sconv_w  = (const float*)d_in[1];
  const float* bn1_g    = (const float*)d_in[2];
  const float* bn1_b    = (const float*)d_in[3];
  const float* bn1_m    = (const float*)d_in[4];
  const float* bn1_v    = (const float*)d_in[5];
  const float* tconv_w  = (const float*)d_in[6];
  const float* bn2_g    = (const float*)d_in[7];
  const float* bn2_b    = (const float*)d_in[8];
  const float* bn2_m    = (const float*)d_in[9];
  const float* bn2_v    = (const float*)d_in[10];
  const float* last_w   = (const float*)d_in[11];
  const float* ln1_g    = (const float*)d_in[12];
  const float* ln1_b    = (const float*)d_in[13];
  const float* in_proj_w= (const float*)d_in[14];
  const float* conv3d_w = (const float*)d_in[15];
  const float* conv3d_b = (const float*)d_in[16];
  const float* m_in_w   = (const float*)d_in[17];
  const float* m_conv_w = (const float*)d_in[18];
  const float* m_conv_b = (const float*)d_in[19];
  const float* m_xproj_w= (const float*)d_in[20];
  const float* m_dtproj_w=(const float*)d_in[21];
  const float* m_dtproj_b=(const float*)d_in[22];
  const float* m_Alog   = (const float*)d_in[23];
  const float* m_D      = (const float*)d_in[24];
  const float* m_out_w  = (const float*)d_in[25];
  const float* out_proj_w=(const float*)d_in[26];
  const float* ln2_g    = (const float*)d_in[27];
  const float* ln2_b    = (const float*)d_in[28];
  const float* fc1_w    = (const float*)d_in[29];
  const float* fc1_b    = (const float*)d_in[30];
  const float* fc2_w    = (const float*)d_in[31];
  const float* fc2_b    = (const float*)d_in[32];
  const float* head_w   = (const float*)d_in[33];
  const float* head_b   = (const float*)d_in[34];

  const size_t WB = 1345536;   // bf16 weight arena bytes
  // pick largest chunk size (videos per pass) whose arena fits ws_size
  int nb = 1;
  for (int cand = 32; cand >= 1; cand >>= 1){
    size_t TPc = (((size_t)cand*LL + 63)/64)*64;
    size_t S2c = (size_t)2*cand*LL;
    size_t need = WB + TPc*2048 + S2c*672;   // pre 160B + ybuf 512B per dir-token
    if (need <= ws_size){ nb = cand; break; }
  }
  const size_t TP  = (((size_t)nb*LL + 63)/64)*64;
  const int S2  = 2*nb;
  const size_t S2T = (size_t)S2*LL;
  const int tokens = nb*LL;

  char* ws = (char*)d_ws;
  __hip_bfloat16* wbf   = (__hip_bfloat16*)(ws);
  size_t o = WB;
  __hip_bfloat16* xb    = (__hip_bfloat16*)(ws + o); o += TP*128;
  __hip_bfloat16* hx    = (__hip_bfloat16*)(ws + o); o += TP*128;
  __hip_bfloat16* xs    = (__hip_bfloat16*)(ws + o); o += TP*256;
  __hip_bfloat16* seq   = (__hip_bfloat16*)(ws + o); o += TP*256;
  __hip_bfloat16* ycomb = xs;                                       // spans xs+seq
  float*          hfin  = (float*)xs;                               // [S2*NCH*256*16] spans xs+seq
  __hip_bfloat16* zblk  = (__hip_bfloat16*)(ws + o); o += TP*256;
  __hip_bfloat16* xm    = (__hip_bfloat16*)(ws + o);
  __hip_bfloat16* yo    = xm;                        o += TP*512;   // yo aliases xm
  __hip_bfloat16* zm    = (__hip_bfloat16*)(ws + o);
  __hip_bfloat16* h2m   = zm;                        o += TP*512;   // h2m aliases zm
  float*          pre   = (float*)(ws + o);          o += S2T*160;
  __hip_bfloat16* ybuf  = (__hip_bfloat16*)(ws + o);                // [S2T,256] (u then y)
  float*          h1s   = (float*)(ws + o);                         // stem tmp aliases ybuf
  float*          h2s   = (float*)(ws + o + (size_t)nb*495616);
  float*          sdtb  = hfin + (size_t)S2*NCH*4096;               // [S2*NCH*256]

  convert_weights<<<2624, 256, 0, stream>>>(in_proj_w, m_in_w, m_out_w, out_proj_w,
                                            fc1_w, fc2_w, m_xproj_w, wbf);

  const int gM = (int)(TP/64);

  for (int b0 = 0; b0 < 32; b0 += nb){
    stem1_kernel<<<nb*484, 256, 0, stream>>>(x, sconv_w, bn1_g, bn1_b, bn1_m, bn1_v, h1s, nb, b0);
    stem2_kernel<<<(nb*116160+255)/256, 256, 0, stream>>>(h1s, tconv_w, bn2_g, bn2_b, bn2_m, bn2_v, h2s, nb);
    stem3_kernel<<<(tokens*64+255)/256, 256, 0, stream>>>(h2s, last_w, xb, tokens);

    for (int i = 0; i < 4; ++i){
      ln_kernel<<<(tokens+3)/4, 256, 0, stream>>>(xb, ln1_g + i*64, ln1_b + i*64, hx, tokens);
      gemm_bf16<0><<<dim3(gM,4), 256, 0, stream>>>(hx, wbf + i*16384, 64, 256, 128, tokens,
                                                   xs, zblk, nullptr, nullptr, nullptr);
      dwconv3d_kernel<<<(tokens*128+255)/256, 256, 0, stream>>>(xs, conv3d_w + i*3456, conv3d_b + i*128, seq, tokens);
      gemm_bf16<0><<<dim3(gM,8), 256, 0, stream>>>(seq, wbf + 65536 + i*65536, 128, 512, 256, tokens,
                                                   xm, zm, nullptr, nullptr, nullptr);
      mamba_pre_kernel<<<S2*57, 256, 0, stream>>>(xm, m_conv_w + i*1024, m_conv_b + i*256,
                                                  wbf + 622592 + i*12288, ybuf, pre, nb);
      scan_p1<<<S2*NCH, 256, 0, stream>>>(ybuf, pre, m_dtproj_w + i*2048, m_dtproj_b + i*256,
                                          m_Alog + i*4096, hfin, sdtb);
      scan_comb<<<S2*16, 256, 0, stream>>>(m_Alog + i*4096, hfin, sdtb);
      scan_p2<<<S2*NCH, 256, 0, stream>>>(ybuf, pre, zm, m_dtproj_w + i*2048, m_dtproj_b + i*256,
                                          m_Alog + i*4096, m_D + i*256, hfin, nb);
      combine_kernel<<<(tokens*256+255)/256, 256, 0, stream>>>(ybuf, ycomb, tokens, nb);
      gemm_bf16<4><<<dim3(gM,2), 256, 0, stream>>>(ycomb, wbf + 327680 + i*32768, 256, 128, 0, tokens,
                                                   yo, nullptr, nullptr, zblk, nullptr);
      gemm_bf16<3><<<dim3(gM,1), 256, 0, stream>>>(yo, wbf + 458752 + i*8192, 128, 64, 0, tokens,
                                                   nullptr, nullptr, nullptr, nullptr, xb);
      ln_kernel<<<(tokens+3)/4, 256, 0, stream>>>(xb, ln2_g + i*64, ln2_b + i*64, hx, tokens);
      gemm_bf16<2><<<dim3(gM,4), 256, 0, stream>>>(hx, wbf + 491520 + i*16384, 64, 256, 0, tokens,
                                                   h2m, nullptr, fc1_b + i*256, nullptr, nullptr);
      gemm_bf16<3><<<dim3(gM,1), 256, 0, stream>>>(h2m, wbf + 557056 + i*16384, 256, 64, 0, tokens,
                                                   nullptr, nullptr, fc2_b + i*64, nullptr, xb);
    }
    head_kernel<<<nb, 256, 0, stream>>>(xb, head_w, head_b, (float*)d_out, b0);
  }
}

// Round 5
// 7063.840 us; speedup vs baseline: 4.2453x; 1.1100x over previous
//
#include <hip/hip_runtime.h>
#include <hip/hip_bf16.h>
#include <hip/hip_fp16.h>

#define LL    3630
#define EPSV  1e-5f
#define NCH   33      // scan chunks
#define CLEN  110     // LL = NCH*CLEN

typedef short bf16x8 __attribute__((ext_vector_type(8)));
typedef float f32x4  __attribute__((ext_vector_type(4)));

__device__ __forceinline__ float bf2f(__hip_bfloat16 x){ return __bfloat162float(x); }
__device__ __forceinline__ __hip_bfloat16 f2bf(float x){ return __float2bfloat16(x); }
__device__ __forceinline__ float siluf(float x){ return x / (1.f + __expf(-x)); }

// ======================= weight f32 -> bf16 =======================
// 0..65535 in_proj | ..327679 m_in | ..458751 m_out | ..491519 out_proj |
// ..557055 fc1 | ..622591 fc2 | ..671743 xproj padded 4x[48][256] (rows40-47 = 0)
__global__ __launch_bounds__(256) void convert_weights(
    const float* __restrict__ s0, const float* __restrict__ s1,
    const float* __restrict__ s2, const float* __restrict__ s3,
    const float* __restrict__ s4, const float* __restrict__ s5,
    const float* __restrict__ s6,
    __hip_bfloat16* __restrict__ dst)
{
  int gid = blockIdx.x*256 + threadIdx.x;
  float v;
  if      (gid <  65536) v = s0[gid];
  else if (gid < 327680) v = s1[gid-65536];
  else if (gid < 458752) v = s2[gid-327680];
  else if (gid < 491520) v = s3[gid-458752];
  else if (gid < 557056) v = s4[gid-491520];
  else if (gid < 622592) v = s5[gid-557056];
  else if (gid < 671744){
    int rel = gid - 622592;
    int layer = rel / 12288;
    int rr  = (rel % 12288) / 256;
    int ccol= rel & 255;
    v = (rr < 40) ? s6[layer*10240 + rr*256 + ccol] : 0.f;
  }
  else return;
  dst[gid] = f2bf(v);
}

// ======================= stem =======================
__global__ __launch_bounds__(256) void stem1_kernel(
    const float* __restrict__ x, const float* __restrict__ w,
    const float* __restrict__ g, const float* __restrict__ bb,
    const float* __restrict__ mm, const float* __restrict__ vv,
    float* __restrict__ out, int nb, int b0)
{
  int idx = blockIdx.x*256 + threadIdx.x;
  if (idx >= nb*123904) return;
  int j = idx % 11;
  int i = (idx/11) % 11;
  int t = (idx/121) % 32;
  int c = (idx/(121*32)) % 32;
  int b = idx/(121*32*32);
  const float* xp = x + ((b0+b)*32 + t)*169;
  const float* wp = w + c*9;
  float acc = 0.f;
  #pragma unroll
  for (int di=0; di<3; ++di)
    #pragma unroll
    for (int dj=0; dj<3; ++dj)
      acc += xp[(i+di)*13 + (j+dj)] * wp[di*3+dj];
  float s = g[c]*rsqrtf(vv[c]+EPSV);
  acc = acc*s + (bb[c]-mm[c]*s);
  out[idx] = fmaxf(acc, 0.f);
}

__global__ __launch_bounds__(256) void stem2_kernel(
    const float* __restrict__ h1, const float* __restrict__ w,
    const float* __restrict__ g, const float* __restrict__ bb,
    const float* __restrict__ mm, const float* __restrict__ vv,
    float* __restrict__ out, int nb)
{
  int idx = blockIdx.x*256 + threadIdx.x;
  if (idx >= nb*116160) return;
  int ij = idx % 121;
  int t  = (idx/121) % 30;
  int c  = (idx/(121*30)) % 32;
  int b  = idx/(121*30*32);
  const float* hp = h1 + ((b*32+c)*32)*121 + ij;
  const float* wp = w + c*3;
  float acc = 0.f;
  #pragma unroll
  for (int k=0;k<3;++k) acc += hp[(t+k)*121] * wp[k];
  float s = g[c]*rsqrtf(vv[c]+EPSV);
  acc = acc*s + (bb[c]-mm[c]*s);
  out[idx] = fmaxf(acc, 0.f);
}

__global__ __launch_bounds__(256) void stem3_kernel(
    const float* __restrict__ h2, const float* __restrict__ w,
    __hip_bfloat16* __restrict__ xb, int tokens)
{
  int gid = blockIdx.x*256 + threadIdx.x;
  int cc = gid & 63;
  int tok = gid >> 6;
  if (tok >= tokens) return;
  int ij = tok % 121;
  int t  = (tok/121) % 30;
  int b  = tok/LL;
  const float* hp = h2 + ((long)b*32)*30*121 + t*121 + ij;
  const float* wp = w + cc*32;
  float acc = 0.f;
  #pragma unroll
  for (int ci=0; ci<32; ++ci) acc += hp[ci*3630] * wp[ci];
  xb[(long)tok*64+cc] = f2bf(acc);
}

// ======================= layernorm (dim 64), bf16 in/out =======================
__global__ __launch_bounds__(256) void ln_kernel(
    const __hip_bfloat16* __restrict__ xb, const float* __restrict__ g,
    const float* __restrict__ b2, __hip_bfloat16* __restrict__ out, int tokens)
{
  int wid = threadIdx.x >> 6, lane = threadIdx.x & 63;
  long tok = (long)blockIdx.x*4 + wid;
  if (tok >= tokens) return;
  float v = bf2f(xb[tok*64 + lane]);
  float s = v, q = v*v;
  #pragma unroll
  for (int m=1; m<64; m<<=1){ s += __shfl_xor(s,m); q += __shfl_xor(q,m); }
  float mean = s*(1.f/64.f);
  float var  = q*(1.f/64.f) - mean*mean;
  float o = (v-mean)*rsqrtf(var+EPSV)*g[lane] + b2[lane];
  out[tok*64+lane] = f2bf(o);
}

// ======================= bf16 MFMA GEMM: out[M,N] = A[M,K] @ W[N,K]^T =======================
// 128-row blocks: 4 waves x 32 rows (2 A-frags, 4 B-frags, 8 MFMA per k-step)
template<int EPI>
__global__ __launch_bounds__(256) void gemm_bf16(
    const __hip_bfloat16* __restrict__ A, const __hip_bfloat16* __restrict__ W,
    int K, int N, int NH, int tokens,
    __hip_bfloat16* __restrict__ out1, __hip_bfloat16* __restrict__ out2,
    const float* __restrict__ bias, const __hip_bfloat16* __restrict__ gate,
    __hip_bfloat16* __restrict__ resid)
{
  int w   = threadIdx.x >> 6;
  int lane= threadIdx.x & 63;
  int r16 = lane & 15;
  int kg  = lane >> 4;          // 0..3
  long m0 = (long)blockIdx.x*128 + w*32;
  int  n0 = blockIdx.y*64;
  long ra0 = m0 + r16;      if (ra0 > tokens-1) ra0 = tokens-1;
  long ra1 = m0 + 16 + r16; if (ra1 > tokens-1) ra1 = tokens-1;
  f32x4 acc[2][4] = { { {0,0,0,0},{0,0,0,0},{0,0,0,0},{0,0,0,0} },
                      { {0,0,0,0},{0,0,0,0},{0,0,0,0},{0,0,0,0} } };
  for (int k0 = 0; k0 < K; k0 += 32){
    bf16x8 a0 = *reinterpret_cast<const bf16x8*>(A + ra0*K + k0 + kg*8);
    bf16x8 a1 = *reinterpret_cast<const bf16x8*>(A + ra1*K + k0 + kg*8);
    #pragma unroll
    for (int f=0; f<4; ++f){
      bf16x8 b = *reinterpret_cast<const bf16x8*>(W + (long)(n0 + f*16 + r16)*K + k0 + kg*8);
      acc[0][f] = __builtin_amdgcn_mfma_f32_16x16x32_bf16(a0, b, acc[0][f], 0, 0, 0);
      acc[1][f] = __builtin_amdgcn_mfma_f32_16x16x32_bf16(a1, b, acc[1][f], 0, 0, 0);
    }
  }
  #pragma unroll
  for (int g2=0; g2<2; ++g2){
    #pragma unroll
    for (int f=0; f<4; ++f){
      int col = n0 + f*16 + r16;
      #pragma unroll
      for (int r=0; r<4; ++r){
        long row = m0 + g2*16 + kg*4 + r;
        if (row >= tokens) continue;
        float v = acc[g2][f][r];
        if (EPI == 0){
          if (col < NH) out1[row*NH + col] = f2bf(v);
          else          out2[row*NH + col - NH] = f2bf(siluf(v));
        } else if (EPI == 2){
          v += bias[col];
          v = 0.5f*v*(1.f + erff(v*0.70710678118f));
          out1[row*N + col] = f2bf(v);
        } else if (EPI == 3){
          if (bias) v += bias[col];
          resid[row*N + col] = f2bf(v + bf2f(resid[row*N + col]));
        } else {
          out1[row*N + col] = f2bf(v * bf2f(gate[row*N + col]));
        }
      }
    }
  }
}

// ======================= depthwise conv3d 3x3x3 SAME + silu =======================
__global__ __launch_bounds__(256) void dwconv3d_kernel(
    const __hip_bfloat16* __restrict__ xs, const float* __restrict__ w,
    const float* __restrict__ bias, __hip_bfloat16* __restrict__ seq, int tokens)
{
  long gid = (long)blockIdx.x*256 + threadIdx.x;
  int c = gid & 127;
  long tok = gid >> 7;
  if (tok >= tokens) return;
  int j  = tok % 11;
  int i2 = (tok/11) % 11;
  int t  = (tok/121) % 30;
  long b = tok/LL;
  const float* wc = w + c*27;
  float acc = bias[c];
  #pragma unroll
  for (int dt=0; dt<3; ++dt){
    int tt = t+dt-1; if (tt<0 || tt>=30) continue;
    #pragma unroll
    for (int di=0; di<3; ++di){
      int ii = i2+di-1; if (ii<0 || ii>=11) continue;
      #pragma unroll
      for (int dj=0; dj<3; ++dj){
        int jj = j+dj-1; if (jj<0 || jj>=11) continue;
        long t2 = (b*30+tt)*121 + ii*11 + jj;
        acc += wc[dt*9+di*3+dj] * bf2f(xs[t2*128 + c]);
      }
    }
  }
  seq[tok*128 + c] = f2bf(siluf(acc));
}

// ======================= mamba_pre: conv1d+silu -> LDS + u out, xproj via MFMA =======================
// grid = 2nb sequences * 57 chunks of 64 tokens; block 256 (4 waves)
__global__ __launch_bounds__(256) void mamba_pre_kernel(
    const __hip_bfloat16* __restrict__ xm,       // [nb, L, 256] fwd-order raw x
    const float* __restrict__ cw, const float* __restrict__ cbv,
    const __hip_bfloat16* __restrict__ xpw_bf,   // [48,256] zero-padded
    __hip_bfloat16* __restrict__ ub,
    float* __restrict__ pre,
    int nb)
{
  __shared__ __hip_bfloat16 xcs[64][264];   // +8 pad
  int s  = blockIdx.x / 57;
  int ch = blockIdx.x % 57;
  int p0 = ch*64;
  int b  = s % nb;
  bool fwd = s < nb;
  int d = threadIdx.x;
  const long basex = (long)b*LL*256 + d;
  const long sLL = (long)s*LL;
  float w0=cw[d*4], w1=cw[d*4+1], w2=cw[d*4+2], w3=cw[d*4+3], cb=cbv[d];
  float p1=0.f, p2=0.f, p3=0.f;
  if (p0-1 >= 0) p1 = bf2f(xm[basex + (long)(fwd ? p0-1 : LL-p0  )*256]);
  if (p0-2 >= 0) p2 = bf2f(xm[basex + (long)(fwd ? p0-2 : LL+1-p0)*256]);
  if (p0-3 >= 0) p3 = bf2f(xm[basex + (long)(fwd ? p0-3 : LL+2-p0)*256]);
  for (int t=0; t<64; ++t){
    int p = p0 + t;
    float xl = 0.f;
    if (p < LL) xl = bf2f(xm[basex + (long)(fwd ? p : LL-1-p)*256]);
    float xc = w3*xl + w2*p1 + w1*p2 + w0*p3 + cb;
    p3=p2; p2=p1; p1=xl;
    __hip_bfloat16 uv = f2bf(siluf(xc));
    xcs[t][d] = uv;
    if (p < LL) ub[(sLL + p)*256 + d] = uv;
  }
  __syncthreads();
  int w = threadIdx.x >> 6, lane = threadIdx.x & 63;
  int r16 = lane & 15, kg = lane >> 4;
  int t0 = w*16;
  f32x4 acc[3] = { {0,0,0,0},{0,0,0,0},{0,0,0,0} };
  for (int k0=0; k0<256; k0+=32){
    bf16x8 a = *reinterpret_cast<const bf16x8*>(&xcs[t0+r16][k0+kg*8]);
    #pragma unroll
    for (int f=0; f<3; ++f){
      bf16x8 bb = *reinterpret_cast<const bf16x8*>(xpw_bf + (f*16+r16)*256 + k0 + kg*8);
      acc[f] = __builtin_amdgcn_mfma_f32_16x16x32_bf16(a, bb, acc[f], 0, 0, 0);
    }
  }
  #pragma unroll
  for (int f=0; f<3; ++f){
    int col = f*16 + r16;
    #pragma unroll
    for (int r=0; r<4; ++r){
      int tl = t0 + kg*4 + r;
      int p = p0 + tl;
      if (p >= LL) continue;
      if (col < 40) pre[(sLL + p)*40 + col] = acc[f][r];
    }
  }
}

// ======================= chunked selective scan, lane = d =======================
__global__ __launch_bounds__(256) void scan_p1(
    const __hip_bfloat16* __restrict__ ub,   // [2nb,L,256]
    const float* __restrict__ pre,           // [2nb,L,40]
    const float* __restrict__ dtw, const float* __restrict__ dtbv,
    const float* __restrict__ Alog,
    float* __restrict__ hfin, float* __restrict__ sdt)
{
  int d = threadIdx.x;
  int sc = blockIdx.x;
  int ch = sc % NCH, s = sc / NCH;
  float a2[16];
  #pragma unroll
  for (int n=0;n<16;++n) a2[n] = -__expf(Alog[d*16+n]) * 1.44269504f;
  float dw[8];
  #pragma unroll
  for (int r=0;r<8;++r) dw[r] = dtw[d*8+r];
  float dtb_d = dtbv[d];
  float h[16];
  #pragma unroll
  for (int n=0;n<16;++n) h[n] = 0.f;
  float sacc = 0.f;
  long tok0 = (long)s*LL + ch*CLEN;
  long ui = tok0*256 + d;
  long pi = tok0*40;
  for (int l=0; l<CLEN; ++l){
    float u = bf2f(ub[ui]);
    float4 r0 = *reinterpret_cast<const float4*>(pre+pi);
    float4 r1 = *reinterpret_cast<const float4*>(pre+pi+4);
    float xacc = dtb_d;
    xacc = fmaf(r0.x,dw[0],fmaf(r0.y,dw[1],fmaf(r0.z,dw[2],fmaf(r0.w,dw[3],xacc))));
    xacc = fmaf(r1.x,dw[4],fmaf(r1.y,dw[5],fmaf(r1.z,dw[6],fmaf(r1.w,dw[7],xacc))));
    float dt = (xacc > 20.f) ? xacc : __logf(1.f + __expf(xacc));
    sacc += dt;
    float dtu = dt*u;
    float4 B0 = *reinterpret_cast<const float4*>(pre+pi+8);
    float4 B1 = *reinterpret_cast<const float4*>(pre+pi+12);
    float4 B2 = *reinterpret_cast<const float4*>(pre+pi+16);
    float4 B3 = *reinterpret_cast<const float4*>(pre+pi+20);
    float Bv[16];
    Bv[0]=B0.x; Bv[1]=B0.y; Bv[2]=B0.z; Bv[3]=B0.w;
    Bv[4]=B1.x; Bv[5]=B1.y; Bv[6]=B1.z; Bv[7]=B1.w;
    Bv[8]=B2.x; Bv[9]=B2.y; Bv[10]=B2.z; Bv[11]=B2.w;
    Bv[12]=B3.x; Bv[13]=B3.y; Bv[14]=B3.z; Bv[15]=B3.w;
    #pragma unroll
    for (int n=0;n<16;++n){
      float e = exp2f(dt*a2[n]);
      h[n] = fmaf(e, h[n], dtu*Bv[n]);
    }
    ui += 256; pi += 40;
  }
  long hbase = ((long)sc*256 + d)*16;
  #pragma unroll
  for (int n=0;n<16;++n) hfin[hbase+n] = h[n];
  sdt[(long)sc*256 + d] = sacc;
}

// sequential chunk combine (in-place: hfin becomes hinit)
__global__ __launch_bounds__(256) void scan_comb(
    const float* __restrict__ Alog,
    float* __restrict__ hfin, const float* __restrict__ sdt)
{
  int s = blockIdx.x >> 4, dg = blockIdx.x & 15;
  int d = dg*16 + (threadIdx.x >> 4), n = threadIdx.x & 15;
  float a2 = -__expf(Alog[d*16+n]) * 1.44269504f;
  float h = 0.f;
  for (int ch=0; ch<NCH; ++ch){
    long sc = (long)s*NCH + ch;
    long idx = (sc*256 + d)*16 + n;
    float hf = hfin[idx];
    float sd = sdt[sc*256 + d];
    hfin[idx] = h;
    h = exp2f(a2*sd)*h + hf;
  }
}

// pass2: rescan chunk from hinit; write raw y (+u*D) over ub in-place
__global__ __launch_bounds__(256) void scan_p2(
    __hip_bfloat16* __restrict__ ub,         // [2nb,L,256] in: u, out: y
    const float* __restrict__ pre,
    const float* __restrict__ dtw, const float* __restrict__ dtbv,
    const float* __restrict__ Alog, const float* __restrict__ Dv,
    const float* __restrict__ hinit)
{
  int d = threadIdx.x;
  int sc = blockIdx.x;
  int ch = sc % NCH, s = sc / NCH;
  float a2[16];
  #pragma unroll
  for (int n=0;n<16;++n) a2[n] = -__expf(Alog[d*16+n]) * 1.44269504f;
  float dw[8];
  #pragma unroll
  for (int r=0;r<8;++r) dw[r] = dtw[d*8+r];
  float dtb_d = dtbv[d];
  float dpv = Dv[d];
  float h[16];
  long hbase = ((long)sc*256 + d)*16;
  #pragma unroll
  for (int n=0;n<16;++n) h[n] = hinit[hbase+n];
  int l0 = ch*CLEN;
  long tok0 = (long)s*LL + l0;
  long ui = tok0*256 + d;
  long pi = tok0*40;
  for (int l=0; l<CLEN; ++l){
    float u = bf2f(ub[ui]);
    float4 r0 = *reinterpret_cast<const float4*>(pre+pi);
    float4 r1 = *reinterpret_cast<const float4*>(pre+pi+4);
    float xacc = dtb_d;
    xacc = fmaf(r0.x,dw[0],fmaf(r0.y,dw[1],fmaf(r0.z,dw[2],fmaf(r0.w,dw[3],xacc))));
    xacc = fmaf(r1.x,dw[4],fmaf(r1.y,dw[5],fmaf(r1.z,dw[6],fmaf(r1.w,dw[7],xacc))));
    float dt = (xacc > 20.f) ? xacc : __logf(1.f + __expf(xacc));
    float dtu = dt*u;
    float4 B0 = *reinterpret_cast<const float4*>(pre+pi+8);
    float4 B1 = *reinterpret_cast<const float4*>(pre+pi+12);
    float4 B2 = *reinterpret_cast<const float4*>(pre+pi+16);
    float4 B3 = *reinterpret_cast<const float4*>(pre+pi+20);
    float4 C0 = *reinterpret_cast<const float4*>(pre+pi+24);
    float4 C1 = *reinterpret_cast<const float4*>(pre+pi+28);
    float4 C2 = *reinterpret_cast<const float4*>(pre+pi+32);
    float4 C3 = *reinterpret_cast<const float4*>(pre+pi+36);
    float Bv[16], Cv[16];
    Bv[0]=B0.x; Bv[1]=B0.y; Bv[2]=B0.z; Bv[3]=B0.w;
    Bv[4]=B1.x; Bv[5]=B1.y; Bv[6]=B1.z; Bv[7]=B1.w;
    Bv[8]=B2.x; Bv[9]=B2.y; Bv[10]=B2.z; Bv[11]=B2.w;
    Bv[12]=B3.x; Bv[13]=B3.y; Bv[14]=B3.z; Bv[15]=B3.w;
    Cv[0]=C0.x; Cv[1]=C0.y; Cv[2]=C0.z; Cv[3]=C0.w;
    Cv[4]=C1.x; Cv[5]=C1.y; Cv[6]=C1.z; Cv[7]=C1.w;
    Cv[8]=C2.x; Cv[9]=C2.y; Cv[10]=C2.z; Cv[11]=C2.w;
    Cv[12]=C3.x; Cv[13]=C3.y; Cv[14]=C3.z; Cv[15]=C3.w;
    float y = 0.f;
    #pragma unroll
    for (int n=0;n<16;++n){
      float e = exp2f(dt*a2[n]);
      h[n] = fmaf(e, h[n], dtu*Bv[n]);
      y = fmaf(h[n], Cv[n], y);
    }
    ub[ui] = f2bf(y + u*dpv);
    ui += 256; pi += 40;
  }
}

// ======================= combine fwd/bwd + zm gate =======================
__global__ __launch_bounds__(256) void combine_kernel(
    const __hip_bfloat16* __restrict__ yb, const __hip_bfloat16* __restrict__ zm,
    __hip_bfloat16* __restrict__ ycomb, int tokens, int nb)
{
  long gid = (long)blockIdx.x*256 + threadIdx.x;
  long tok = gid >> 8;
  if (tok >= tokens) return;
  int c = gid & 255;
  long l = tok % LL, b = tok / LL;
  float vf = bf2f(yb[( b*LL + l)*256 + c]);
  float vb = bf2f(yb[((nb+b)*LL + (LL-1-l))*256 + c]);
  ycomb[gid] = f2bf((vf+vb)*bf2f(zm[gid]));
}

// ======================= head: two-stage mean + linear =======================
__global__ __launch_bounds__(256) void head1_kernel(
    const __hip_bfloat16* __restrict__ xb, float* __restrict__ hp)
{
  __shared__ float partial[4][64];
  int b = blockIdx.x / 30, ch = blockIdx.x % 30;
  int d = threadIdx.x & 63, part = threadIdx.x >> 6;
  float acc = 0.f;
  int lend = (ch+1)*121;
  for (int l = ch*121 + part; l < lend; l += 4)
    acc += bf2f(xb[((long)b*LL + l)*64 + d]);
  partial[part][d] = acc;
  __syncthreads();
  if (part == 0)
    hp[(b*30 + ch)*64 + d] = partial[0][d]+partial[1][d]+partial[2][d]+partial[3][d];
}

__global__ __launch_bounds__(64) void head2_kernel(
    const float* __restrict__ hp, const float* __restrict__ hw,
    const float* __restrict__ hb, float* __restrict__ out, int b0)
{
  __shared__ float feat[64];
  int b = blockIdx.x;
  int d = threadIdx.x;
  float acc = 0.f;
  #pragma unroll
  for (int ch=0; ch<30; ++ch) acc += hp[(b*30+ch)*64 + d];
  float f = acc * (1.f/3630.f);
  feat[d] = f;
  out[512 + (b0+b)*64 + d] = f;
  __syncthreads();
  if (d < 16){
    float a2 = hb[d];
    #pragma unroll
    for (int k=0; k<64; ++k) a2 += feat[k]*hw[d*64+k];
    out[(b0+b)*16 + d] = a2;
  }
}

// ======================= launch =======================
extern "C" void kernel_launch(void* const* d_in, const int* in_sizes, int n_in,
                              void* d_out, int out_size, void* d_ws, size_t ws_size,
                              hipStream_t stream)
{
  const float* x        = (const float*)d_in[0];
  const float* sconv_w  = (const float*)d_in[1];
  const float* bn1_g    = (const float*)d_in[2];
  const float* bn1_b    = (const float*)d_in[3];
  const float* bn1_m    = (const float*)d_in[4];
  const float* bn1_v    = (const float*)d_in[5];
  const float* tconv_w  = (const float*)d_in[6];
  const float* bn2_g    = (const float*)d_in[7];
  const float* bn2_b    = (const float*)d_in[8];
  const float* bn2_m    = (const float*)d_in[9];
  const float* bn2_v    = (const float*)d_in[10];
  const float* last_w   = (const float*)d_in[11];
  const float* ln1_g    = (const float*)d_in[12];
  const float* ln1_b    = (const float*)d_in[13];
  const float* in_proj_w= (const float*)d_in[14];
  const float* conv3d_w = (const float*)d_in[15];
  const float* conv3d_b = (const float*)d_in[16];
  const float* m_in_w   = (const float*)d_in[17];
  const float* m_conv_w = (const float*)d_in[18];
  const float* m_conv_b = (const float*)d_in[19];
  const float* m_xproj_w= (const float*)d_in[20];
  const float* m_dtproj_w=(const float*)d_in[21];
  const float* m_dtproj_b=(const float*)d_in[22];
  const float* m_Alog   = (const float*)d_in[23];
  const float* m_D      = (const float*)d_in[24];
  const float* m_out_w  = (const float*)d_in[25];
  const float* out_proj_w=(const float*)d_in[26];
  const float* ln2_g    = (const float*)d_in[27];
  const float* ln2_b    = (const float*)d_in[28];
  const float* fc1_w    = (const float*)d_in[29];
  const float* fc1_b    = (const float*)d_in[30];
  const float* fc2_w    = (const float*)d_in[31];
  const float* fc2_b    = (const float*)d_in[32];
  const float* head_w   = (const float*)d_in[33];
  const float* head_b   = (const float*)d_in[34];

  const size_t WB = 1345536;   // bf16 weight arena bytes
  int nb = 1;
  for (int cand = 32; cand >= 1; cand >>= 1){
    size_t TPc = (((size_t)cand*LL + 63)/64)*64;
    size_t S2c = (size_t)2*cand*LL;
    size_t need = WB + TPc*2048 + S2c*672;
    if (need <= ws_size){ nb = cand; break; }
  }
  const size_t TP  = (((size_t)nb*LL + 63)/64)*64;
  const int S2  = 2*nb;
  const size_t S2T = (size_t)S2*LL;
  const int tokens = nb*LL;

  char* ws = (char*)d_ws;
  __hip_bfloat16* wbf   = (__hip_bfloat16*)(ws);
  size_t o = WB;
  __hip_bfloat16* xb    = (__hip_bfloat16*)(ws + o); o += TP*128;
  __hip_bfloat16* hx    = (__hip_bfloat16*)(ws + o); o += TP*128;
  float*          hp    = (float*)hx;                               // head partials (hx dead at head)
  __hip_bfloat16* xs    = (__hip_bfloat16*)(ws + o); o += TP*256;
  __hip_bfloat16* seq   = (__hip_bfloat16*)(ws + o); o += TP*256;
  __hip_bfloat16* ycomb = xs;                                       // spans xs+seq
  float*          hfin  = (float*)xs;                               // spans xs+seq
  __hip_bfloat16* zblk  = (__hip_bfloat16*)(ws + o); o += TP*256;
  __hip_bfloat16* xm    = (__hip_bfloat16*)(ws + o);
  __hip_bfloat16* yo    = xm;                        o += TP*512;   // yo aliases xm
  __hip_bfloat16* zm    = (__hip_bfloat16*)(ws + o);
  __hip_bfloat16* h2m   = zm;                        o += TP*512;   // h2m aliases zm
  float*          pre   = (float*)(ws + o);          o += S2T*160;
  __hip_bfloat16* ybuf  = (__hip_bfloat16*)(ws + o);                // [S2T,256] (u then y)
  float*          h1s   = (float*)(ws + o);                         // stem tmp aliases ybuf
  float*          h2s   = (float*)(ws + o + (size_t)nb*495616);
  float*          sdtb  = hfin + (size_t)S2*NCH*4096;               // [S2*NCH*256]

  convert_weights<<<2624, 256, 0, stream>>>(in_proj_w, m_in_w, m_out_w, out_proj_w,
                                            fc1_w, fc2_w, m_xproj_w, wbf);

  const int gM2 = (int)((TP + 127)/128);

  for (int b0 = 0; b0 < 32; b0 += nb){
    stem1_kernel<<<nb*484, 256, 0, stream>>>(x, sconv_w, bn1_g, bn1_b, bn1_m, bn1_v, h1s, nb, b0);
    stem2_kernel<<<(nb*116160+255)/256, 256, 0, stream>>>(h1s, tconv_w, bn2_g, bn2_b, bn2_m, bn2_v, h2s, nb);
    stem3_kernel<<<(tokens*64+255)/256, 256, 0, stream>>>(h2s, last_w, xb, tokens);

    for (int i = 0; i < 4; ++i){
      ln_kernel<<<(tokens+3)/4, 256, 0, stream>>>(xb, ln1_g + i*64, ln1_b + i*64, hx, tokens);
      gemm_bf16<0><<<dim3(gM2,4), 256, 0, stream>>>(hx, wbf + i*16384, 64, 256, 128, tokens,
                                                    xs, zblk, nullptr, nullptr, nullptr);
      dwconv3d_kernel<<<(tokens*128+255)/256, 256, 0, stream>>>(xs, conv3d_w + i*3456, conv3d_b + i*128, seq, tokens);
      gemm_bf16<0><<<dim3(gM2,8), 256, 0, stream>>>(seq, wbf + 65536 + i*65536, 128, 512, 256, tokens,
                                                    xm, zm, nullptr, nullptr, nullptr);
      mamba_pre_kernel<<<S2*57, 256, 0, stream>>>(xm, m_conv_w + i*1024, m_conv_b + i*256,
                                                  wbf + 622592 + i*12288, ybuf, pre, nb);
      scan_p1<<<S2*NCH, 256, 0, stream>>>(ybuf, pre, m_dtproj_w + i*2048, m_dtproj_b + i*256,
                                          m_Alog + i*4096, hfin, sdtb);
      scan_comb<<<S2*16, 256, 0, stream>>>(m_Alog + i*4096, hfin, sdtb);
      scan_p2<<<S2*NCH, 256, 0, stream>>>(ybuf, pre, m_dtproj_w + i*2048, m_dtproj_b + i*256,
                                          m_Alog + i*4096, m_D + i*256, hfin);
      combine_kernel<<<(tokens*256+255)/256, 256, 0, stream>>>(ybuf, zm, ycomb, tokens, nb);
      gemm_bf16<4><<<dim3(gM2,2), 256, 0, stream>>>(ycomb, wbf + 327680 + i*32768, 256, 128, 0, tokens,
                                                    yo, nullptr, nullptr, zblk, nullptr);
      gemm_bf16<3><<<dim3(gM2,1), 256, 0, stream>>>(yo, wbf + 458752 + i*8192, 128, 64, 0, tokens,
                                                    nullptr, nullptr, nullptr, nullptr, xb);
      ln_kernel<<<(tokens+3)/4, 256, 0, stream>>>(xb, ln2_g + i*64, ln2_b + i*64, hx, tokens);
      gemm_bf16<2><<<dim3(gM2,4), 256, 0, stream>>>(hx, wbf + 491520 + i*16384, 64, 256, 0, tokens,
                                                    h2m, nullptr, fc1_b + i*256, nullptr, nullptr);
      gemm_bf16<3><<<dim3(gM2,1), 256, 0, stream>>>(h2m, wbf + 557056 + i*16384, 256, 64, 0, tokens,
                                                    nullptr, nullptr, fc2_b + i*64, nullptr, xb);
    }
    head1_kernel<<<nb*30, 256, 0, stream>>>(xb, hp);
    head2_kernel<<<nb, 64, 0, stream>>>(hp, head_w, head_b, (float*)d_out, b0);
  }
}

// Round 7
// 6705.587 us; speedup vs baseline: 4.4721x; 1.0534x over previous
//
#include <hip/hip_runtime.h>
#include <hip/hip_bf16.h>
#include <hip/hip_fp16.h>

#define LL    3630
#define EPSV  1e-5f
#define NCH   33      // scan chunks
#define CLEN  110     // LL = NCH*CLEN

typedef short bf16x8 __attribute__((ext_vector_type(8)));
typedef float f32x4  __attribute__((ext_vector_type(4)));
typedef float f32x2  __attribute__((ext_vector_type(2)));
typedef float f32x16 __attribute__((ext_vector_type(16)));

__device__ __forceinline__ float bf2f(__hip_bfloat16 x){ return __bfloat162float(x); }
__device__ __forceinline__ __hip_bfloat16 f2bf(float x){ return __float2bfloat16(x); }
__device__ __forceinline__ float siluf(float x){ return x / (1.f + __expf(-x)); }
__device__ __forceinline__ float s2f(short s){ __hip_bfloat16 t = __builtin_bit_cast(__hip_bfloat16, s); return __bfloat162float(t); }
__device__ __forceinline__ short f2s(float x){ __hip_bfloat16 t = __float2bfloat16(x); return __builtin_bit_cast(short, t); }

// ======================= weight f32 -> bf16 =======================
__global__ __launch_bounds__(256) void convert_weights(
    const float* __restrict__ s0, const float* __restrict__ s1,
    const float* __restrict__ s2, const float* __restrict__ s3,
    const float* __restrict__ s4, const float* __restrict__ s5,
    const float* __restrict__ s6,
    __hip_bfloat16* __restrict__ dst)
{
  int gid = blockIdx.x*256 + threadIdx.x;
  float v;
  if      (gid <  65536) v = s0[gid];
  else if (gid < 327680) v = s1[gid-65536];
  else if (gid < 458752) v = s2[gid-327680];
  else if (gid < 491520) v = s3[gid-458752];
  else if (gid < 557056) v = s4[gid-491520];
  else if (gid < 622592) v = s5[gid-557056];
  else if (gid < 671744){
    int rel = gid - 622592;
    int layer = rel / 12288;
    int rr  = (rel % 12288) / 256;
    int ccol= rel & 255;
    v = (rr < 40) ? s6[layer*10240 + rr*256 + ccol] : 0.f;
  }
  else return;
  dst[gid] = f2bf(v);
}

// ======================= stem =======================
__global__ __launch_bounds__(256) void stem1_kernel(
    const float* __restrict__ x, const float* __restrict__ w,
    const float* __restrict__ g, const float* __restrict__ bb,
    const float* __restrict__ mm, const float* __restrict__ vv,
    float* __restrict__ out, int nb, int b0)
{
  int idx = blockIdx.x*256 + threadIdx.x;
  if (idx >= nb*123904) return;
  int j = idx % 11;
  int i = (idx/11) % 11;
  int t = (idx/121) % 32;
  int c = (idx/(121*32)) % 32;
  int b = idx/(121*32*32);
  const float* xp = x + ((b0+b)*32 + t)*169;
  const float* wp = w + c*9;
  float acc = 0.f;
  #pragma unroll
  for (int di=0; di<3; ++di)
    #pragma unroll
    for (int dj=0; dj<3; ++dj)
      acc += xp[(i+di)*13 + (j+dj)] * wp[di*3+dj];
  float s = g[c]*rsqrtf(vv[c]+EPSV);
  acc = acc*s + (bb[c]-mm[c]*s);
  out[idx] = fmaxf(acc, 0.f);
}

__global__ __launch_bounds__(256) void stem2_kernel(
    const float* __restrict__ h1, const float* __restrict__ w,
    const float* __restrict__ g, const float* __restrict__ bb,
    const float* __restrict__ mm, const float* __restrict__ vv,
    float* __restrict__ out, int nb)
{
  int idx = blockIdx.x*256 + threadIdx.x;
  if (idx >= nb*116160) return;
  int ij = idx % 121;
  int t  = (idx/121) % 30;
  int c  = (idx/(121*30)) % 32;
  int b  = idx/(121*30*32);
  const float* hp = h1 + ((b*32+c)*32)*121 + ij;
  const float* wp = w + c*3;
  float acc = 0.f;
  #pragma unroll
  for (int k=0;k<3;++k) acc += hp[(t+k)*121] * wp[k];
  float s = g[c]*rsqrtf(vv[c]+EPSV);
  acc = acc*s + (bb[c]-mm[c]*s);
  out[idx] = fmaxf(acc, 0.f);
}

__global__ __launch_bounds__(256) void stem3_kernel(
    const float* __restrict__ h2, const float* __restrict__ w,
    __hip_bfloat16* __restrict__ xb, int tokens)
{
  int gid = blockIdx.x*256 + threadIdx.x;
  int cc = gid & 63;
  int tok = gid >> 6;
  if (tok >= tokens) return;
  int ij = tok % 121;
  int t  = (tok/121) % 30;
  int b  = tok/LL;
  const float* hp = h2 + ((long)b*32)*30*121 + t*121 + ij;
  const float* wp = w + cc*32;
  float acc = 0.f;
  #pragma unroll
  for (int ci=0; ci<32; ++ci) acc += hp[ci*3630] * wp[ci];
  xb[(long)tok*64+cc] = f2bf(acc);
}

// ======================= layernorm (dim 64) — used once per pass =======================
__global__ __launch_bounds__(256) void ln_kernel(
    const __hip_bfloat16* __restrict__ xb, const float* __restrict__ g,
    const float* __restrict__ b2, __hip_bfloat16* __restrict__ out, int tokens)
{
  int wid = threadIdx.x >> 6, lane = threadIdx.x & 63;
  long tok = (long)blockIdx.x*4 + wid;
  if (tok >= tokens) return;
  float v = bf2f(xb[tok*64 + lane]);
  float s = v, q = v*v;
  #pragma unroll
  for (int m=1; m<64; m<<=1){ s += __shfl_xor(s,m); q += __shfl_xor(q,m); }
  float mean = s*(1.f/64.f);
  float var  = q*(1.f/64.f) - mean*mean;
  float o = (v-mean)*rsqrtf(var+EPSV)*g[lane] + b2[lane];
  out[tok*64+lane] = f2bf(o);
}

// ======================= bf16 MFMA GEMM: out[M,N] = A[M,K] @ W[N,K]^T =======================
// EPI 0: split silu; EPI 2: bias+gelu; EPI 3: (+bias)+resid RMW; EPI 4: gate;
// EPI 5 (N=64): (+bias)+resid RMW -> resid, then LayerNorm(lng,lnb) -> out1
template<int EPI>
__global__ __launch_bounds__(256) void gemm_bf16(
    const __hip_bfloat16* __restrict__ A, const __hip_bfloat16* __restrict__ W,
    int K, int N, int NH, int tokens,
    __hip_bfloat16* __restrict__ out1, __hip_bfloat16* __restrict__ out2,
    const float* __restrict__ bias, const __hip_bfloat16* __restrict__ gate,
    __hip_bfloat16* __restrict__ resid,
    const float* __restrict__ lng, const float* __restrict__ lnb)
{
  int w   = threadIdx.x >> 6;
  int lane= threadIdx.x & 63;
  int r16 = lane & 15;
  int kg  = lane >> 4;          // 0..3
  long m0 = (long)blockIdx.x*128 + w*32;
  int  n0 = blockIdx.y*64;
  long ra0 = m0 + r16;      if (ra0 > tokens-1) ra0 = tokens-1;
  long ra1 = m0 + 16 + r16; if (ra1 > tokens-1) ra1 = tokens-1;
  f32x4 acc[2][4] = { { {0,0,0,0},{0,0,0,0},{0,0,0,0},{0,0,0,0} },
                      { {0,0,0,0},{0,0,0,0},{0,0,0,0},{0,0,0,0} } };
  for (int k0 = 0; k0 < K; k0 += 32){
    bf16x8 a0 = *reinterpret_cast<const bf16x8*>(A + ra0*K + k0 + kg*8);
    bf16x8 a1 = *reinterpret_cast<const bf16x8*>(A + ra1*K + k0 + kg*8);
    #pragma unroll
    for (int f=0; f<4; ++f){
      bf16x8 b = *reinterpret_cast<const bf16x8*>(W + (long)(n0 + f*16 + r16)*K + k0 + kg*8);
      acc[0][f] = __builtin_amdgcn_mfma_f32_16x16x32_bf16(a0, b, acc[0][f], 0, 0, 0);
      acc[1][f] = __builtin_amdgcn_mfma_f32_16x16x32_bf16(a1, b, acc[1][f], 0, 0, 0);
    }
  }
  if (EPI == 5){
    // N == 64 fused residual + LayerNorm
    float gv[4], bv[4], biasv[4];
    #pragma unroll
    for (int f=0; f<4; ++f){
      gv[f] = lng[f*16+r16]; bv[f] = lnb[f*16+r16];
      biasv[f] = bias ? bias[f*16+r16] : 0.f;
    }
    #pragma unroll
    for (int g2=0; g2<2; ++g2){
      #pragma unroll
      for (int r=0; r<4; ++r){
        long row = m0 + g2*16 + kg*4 + r;
        bool ok = row < tokens;
        long rowc = ok ? row : (tokens-1);
        float v[4]; float s = 0.f, q = 0.f;
        #pragma unroll
        for (int f=0; f<4; ++f){
          float t = acc[g2][f][r] + biasv[f] + bf2f(resid[rowc*64 + f*16+r16]);
          v[f] = t; s += t; q += t*t;
        }
        #pragma unroll
        for (int m=1; m<16; m<<=1){ s += __shfl_xor(s,m); q += __shfl_xor(q,m); }
        float mean = s*(1.f/64.f);
        float var  = q*(1.f/64.f) - mean*mean;
        float rstd = rsqrtf(var+EPSV);
        if (ok){
          #pragma unroll
          for (int f=0; f<4; ++f){
            resid[row*64 + f*16+r16] = f2bf(v[f]);
            out1 [row*64 + f*16+r16] = f2bf((v[f]-mean)*rstd*gv[f] + bv[f]);
          }
        }
      }
    }
    return;
  }
  #pragma unroll
  for (int g2=0; g2<2; ++g2){
    #pragma unroll
    for (int f=0; f<4; ++f){
      int col = n0 + f*16 + r16;
      #pragma unroll
      for (int r=0; r<4; ++r){
        long row = m0 + g2*16 + kg*4 + r;
        if (row >= tokens) continue;
        float v = acc[g2][f][r];
        if (EPI == 0){
          if (col < NH) out1[row*NH + col] = f2bf(v);
          else          out2[row*NH + col - NH] = f2bf(siluf(v));
        } else if (EPI == 2){
          v += bias[col];
          v = 0.5f*v*(1.f + erff(v*0.70710678118f));
          out1[row*N + col] = f2bf(v);
        } else if (EPI == 3){
          if (bias) v += bias[col];
          resid[row*N + col] = f2bf(v + bf2f(resid[row*N + col]));
        } else {
          out1[row*N + col] = f2bf(v * bf2f(gate[row*N + col]));
        }
      }
    }
  }
}

// ======================= depthwise conv3d 3x3x3 SAME + silu =======================
__global__ __launch_bounds__(256) void dwconv3d_kernel(
    const __hip_bfloat16* __restrict__ xs, const float* __restrict__ w,
    const float* __restrict__ bias, __hip_bfloat16* __restrict__ seq, int tokens)
{
  long gid = (long)blockIdx.x*256 + threadIdx.x;
  int c = gid & 127;
  long tok = gid >> 7;
  if (tok >= tokens) return;
  int j  = tok % 11;
  int i2 = (tok/11) % 11;
  int t  = (tok/121) % 30;
  long b = tok/LL;
  const float* wc = w + c*27;
  float acc = bias[c];
  #pragma unroll
  for (int dt=0; dt<3; ++dt){
    int tt = t+dt-1; if (tt<0 || tt>=30) continue;
    #pragma unroll
    for (int di=0; di<3; ++di){
      int ii = i2+di-1; if (ii<0 || ii>=11) continue;
      #pragma unroll
      for (int dj=0; dj<3; ++dj){
        int jj = j+dj-1; if (jj<0 || jj>=11) continue;
        long t2 = (b*30+tt)*121 + ii*11 + jj;
        acc += wc[dt*9+di*3+dj] * bf2f(xs[t2*128 + c]);
      }
    }
  }
  seq[tok*128 + c] = f2bf(siluf(acc));
}

// ======================= mamba_pre: conv1d+silu -> LDS + u out, xproj via MFMA =======================
__global__ __launch_bounds__(256) void mamba_pre_kernel(
    const __hip_bfloat16* __restrict__ xm,
    const float* __restrict__ cw, const float* __restrict__ cbv,
    const __hip_bfloat16* __restrict__ xpw_bf,
    __hip_bfloat16* __restrict__ ub,
    float* __restrict__ pre,
    int nb)
{
  __shared__ __hip_bfloat16 xcs[64][264];
  int s  = blockIdx.x / 57;
  int ch = blockIdx.x % 57;
  int p0 = ch*64;
  int b  = s % nb;
  bool fwd = s < nb;
  int d = threadIdx.x;
  const long basex = (long)b*LL*256 + d;
  const long sLL = (long)s*LL;
  float w0=cw[d*4], w1=cw[d*4+1], w2=cw[d*4+2], w3=cw[d*4+3], cb=cbv[d];
  float p1=0.f, p2=0.f, p3=0.f;
  if (p0-1 >= 0) p1 = bf2f(xm[basex + (long)(fwd ? p0-1 : LL-p0  )*256]);
  if (p0-2 >= 0) p2 = bf2f(xm[basex + (long)(fwd ? p0-2 : LL+1-p0)*256]);
  if (p0-3 >= 0) p3 = bf2f(xm[basex + (long)(fwd ? p0-3 : LL+2-p0)*256]);
  for (int t=0; t<64; ++t){
    int p = p0 + t;
    float xl = 0.f;
    if (p < LL) xl = bf2f(xm[basex + (long)(fwd ? p : LL-1-p)*256]);
    float xc = w3*xl + w2*p1 + w1*p2 + w0*p3 + cb;
    p3=p2; p2=p1; p1=xl;
    __hip_bfloat16 uv = f2bf(siluf(xc));
    xcs[t][d] = uv;
    if (p < LL) ub[(sLL + p)*256 + d] = uv;
  }
  __syncthreads();
  int w = threadIdx.x >> 6, lane = threadIdx.x & 63;
  int r16 = lane & 15, kg = lane >> 4;
  int t0 = w*16;
  f32x4 acc[3] = { {0,0,0,0},{0,0,0,0},{0,0,0,0} };
  for (int k0=0; k0<256; k0+=32){
    bf16x8 a = *reinterpret_cast<const bf16x8*>(&xcs[t0+r16][k0+kg*8]);
    #pragma unroll
    for (int f=0; f<3; ++f){
      bf16x8 bb = *reinterpret_cast<const bf16x8*>(xpw_bf + (f*16+r16)*256 + k0 + kg*8);
      acc[f] = __builtin_amdgcn_mfma_f32_16x16x32_bf16(a, bb, acc[f], 0, 0, 0);
    }
  }
  #pragma unroll
  for (int f=0; f<3; ++f){
    int col = f*16 + r16;
    #pragma unroll
    for (int r=0; r<4; ++r){
      int tl = t0 + kg*4 + r;
      int p = p0 + tl;
      if (p >= LL) continue;
      if (col < 40) pre[(sLL + p)*40 + col] = acc[f][r];
    }
  }
}

// ======================= chunked selective scan, lane = d, packed f32 =======================
__global__ __launch_bounds__(256) void scan_p1(
    const __hip_bfloat16* __restrict__ ub,
    const float* __restrict__ pre,
    const float* __restrict__ dtw, const float* __restrict__ dtbv,
    const float* __restrict__ Alog,
    float* __restrict__ hfin, float* __restrict__ sdt)
{
  int d = threadIdx.x;
  int sc = blockIdx.x;
  int ch = sc % NCH, s = sc / NCH;
  f32x2 a2[8], h[8];
  #pragma unroll
  for (int k=0;k<8;++k){
    a2[k] = (f32x2){ -__expf(Alog[d*16+2*k])*1.44269504f,
                     -__expf(Alog[d*16+2*k+1])*1.44269504f };
    h[k] = (f32x2){0.f, 0.f};
  }
  float dw[8];
  #pragma unroll
  for (int r=0;r<8;++r) dw[r] = dtw[d*8+r];
  float dtb_d = dtbv[d];
  float sacc = 0.f;
  long tok0 = (long)s*LL + ch*CLEN;
  long ui = tok0*256 + d;
  long pi = tok0*40;
  for (int l=0; l<CLEN; ++l){
    float u = bf2f(ub[ui]);
    float4 r0 = *reinterpret_cast<const float4*>(pre+pi);
    float4 r1 = *reinterpret_cast<const float4*>(pre+pi+4);
    float xacc = dtb_d;
    xacc = fmaf(r0.x,dw[0],fmaf(r0.y,dw[1],fmaf(r0.z,dw[2],fmaf(r0.w,dw[3],xacc))));
    xacc = fmaf(r1.x,dw[4],fmaf(r1.y,dw[5],fmaf(r1.z,dw[6],fmaf(r1.w,dw[7],xacc))));
    float dt = (xacc > 20.f) ? xacc : __logf(1.f + __expf(xacc));
    sacc += dt;
    f32x16 B = *reinterpret_cast<const f32x16*>(pre+pi+8);
    f32x2 dt2  = (f32x2){dt, dt};
    float dtu = dt*u;
    f32x2 dtu2 = (f32x2){dtu, dtu};
    #pragma unroll
    for (int k=0;k<8;++k){
      f32x2 t = dt2*a2[k];
      f32x2 e = (f32x2){ exp2f(t.x), exp2f(t.y) };
      f32x2 bk = (f32x2){ B[2*k], B[2*k+1] };
      h[k] = __builtin_elementwise_fma(e, h[k], dtu2*bk);
    }
    ui += 256; pi += 40;
  }
  long hbase = ((long)sc*256 + d)*16;
  #pragma unroll
  for (int k=0;k<8;++k){ hfin[hbase+2*k] = h[k].x; hfin[hbase+2*k+1] = h[k].y; }
  sdt[(long)sc*256 + d] = sacc;
}

// sequential chunk combine (in-place: hfin becomes hinit)
__global__ __launch_bounds__(256) void scan_comb(
    const float* __restrict__ Alog,
    float* __restrict__ hfin, const float* __restrict__ sdt)
{
  int s = blockIdx.x >> 4, dg = blockIdx.x & 15;
  int d = dg*16 + (threadIdx.x >> 4), n = threadIdx.x & 15;
  float a2 = -__expf(Alog[d*16+n]) * 1.44269504f;
  float h = 0.f;
  for (int ch=0; ch<NCH; ++ch){
    long sc = (long)s*NCH + ch;
    long idx = (sc*256 + d)*16 + n;
    float hf = hfin[idx];
    float sd = sdt[sc*256 + d];
    hfin[idx] = h;
    h = exp2f(a2*sd)*h + hf;
  }
}

// pass2: rescan chunk from hinit; write raw y (+u*D) over ub in-place
__global__ __launch_bounds__(256) void scan_p2(
    __hip_bfloat16* __restrict__ ub,
    const float* __restrict__ pre,
    const float* __restrict__ dtw, const float* __restrict__ dtbv,
    const float* __restrict__ Alog, const float* __restrict__ Dv,
    const float* __restrict__ hinit)
{
  int d = threadIdx.x;
  int sc = blockIdx.x;
  int ch = sc % NCH, s = sc / NCH;
  f32x2 a2[8], h[8];
  long hbase = ((long)sc*256 + d)*16;
  #pragma unroll
  for (int k=0;k<8;++k){
    a2[k] = (f32x2){ -__expf(Alog[d*16+2*k])*1.44269504f,
                     -__expf(Alog[d*16+2*k+1])*1.44269504f };
    h[k] = (f32x2){ hinit[hbase+2*k], hinit[hbase+2*k+1] };
  }
  float dw[8];
  #pragma unroll
  for (int r=0;r<8;++r) dw[r] = dtw[d*8+r];
  float dtb_d = dtbv[d];
  float dpv = Dv[d];
  int l0 = ch*CLEN;
  long tok0 = (long)s*LL + l0;
  long ui = tok0*256 + d;
  long pi = tok0*40;
  for (int l=0; l<CLEN; ++l){
    float u = bf2f(ub[ui]);
    float4 r0 = *reinterpret_cast<const float4*>(pre+pi);
    float4 r1 = *reinterpret_cast<const float4*>(pre+pi+4);
    float xacc = dtb_d;
    xacc = fmaf(r0.x,dw[0],fmaf(r0.y,dw[1],fmaf(r0.z,dw[2],fmaf(r0.w,dw[3],xacc))));
    xacc = fmaf(r1.x,dw[4],fmaf(r1.y,dw[5],fmaf(r1.z,dw[6],fmaf(r1.w,dw[7],xacc))));
    float dt = (xacc > 20.f) ? xacc : __logf(1.f + __expf(xacc));
    f32x16 B = *reinterpret_cast<const f32x16*>(pre+pi+8);
    f32x16 C = *reinterpret_cast<const f32x16*>(pre+pi+24);
    f32x2 dt2  = (f32x2){dt, dt};
    float dtu = dt*u;
    f32x2 dtu2 = (f32x2){dtu, dtu};
    f32x2 y2 = (f32x2){0.f, 0.f};
    #pragma unroll
    for (int k=0;k<8;++k){
      f32x2 t = dt2*a2[k];
      f32x2 e = (f32x2){ exp2f(t.x), exp2f(t.y) };
      f32x2 bk = (f32x2){ B[2*k], B[2*k+1] };
      f32x2 ck = (f32x2){ C[2*k], C[2*k+1] };
      h[k] = __builtin_elementwise_fma(e, h[k], dtu2*bk);
      y2 = __builtin_elementwise_fma(h[k], ck, y2);
    }
    float y = y2.x + y2.y;
    ub[ui] = f2bf(y + u*dpv);
    ui += 256; pi += 40;
  }
}

// ======================= combine fwd/bwd + zm gate (bf16x8 vectorized) =======================
__global__ __launch_bounds__(256) void combine_kernel(
    const __hip_bfloat16* __restrict__ yb, const __hip_bfloat16* __restrict__ zm,
    __hip_bfloat16* __restrict__ ycomb, int tokens, int nb)
{
  long gid = (long)blockIdx.x*256 + threadIdx.x;   // one per 8 channels
  long tok = gid >> 5;
  if (tok >= tokens) return;
  int c8 = (gid & 31) * 8;
  long l = tok % LL, b = tok / LL;
  bf16x8 vf = *reinterpret_cast<const bf16x8*>(yb + ( b*LL + l)*256 + c8);
  bf16x8 vb = *reinterpret_cast<const bf16x8*>(yb + ((nb+b)*LL + (LL-1-l))*256 + c8);
  bf16x8 zz = *reinterpret_cast<const bf16x8*>(zm + tok*256 + c8);
  bf16x8 out;
  #pragma unroll
  for (int k=0;k<8;++k){
    float r = (s2f(vf[k]) + s2f(vb[k])) * s2f(zz[k]);
    out[k] = f2s(r);
  }
  *reinterpret_cast<bf16x8*>(ycomb + tok*256 + c8) = out;
}

// ======================= head: two-stage mean + linear =======================
__global__ __launch_bounds__(256) void head1_kernel(
    const __hip_bfloat16* __restrict__ xb, float* __restrict__ hp)
{
  __shared__ float partial[4][64];
  int b = blockIdx.x / 30, ch = blockIdx.x % 30;
  int d = threadIdx.x & 63, part = threadIdx.x >> 6;
  float acc = 0.f;
  int lend = (ch+1)*121;
  for (int l = ch*121 + part; l < lend; l += 4)
    acc += bf2f(xb[((long)b*LL + l)*64 + d]);
  partial[part][d] = acc;
  __syncthreads();
  if (part == 0)
    hp[(b*30 + ch)*64 + d] = partial[0][d]+partial[1][d]+partial[2][d]+partial[3][d];
}

__global__ __launch_bounds__(64) void head2_kernel(
    const float* __restrict__ hp, const float* __restrict__ hw,
    const float* __restrict__ hb, float* __restrict__ out, int b0)
{
  __shared__ float feat[64];
  int b = blockIdx.x;
  int d = threadIdx.x;
  float acc = 0.f;
  #pragma unroll
  for (int ch=0; ch<30; ++ch) acc += hp[(b*30+ch)*64 + d];
  float f = acc * (1.f/3630.f);
  feat[d] = f;
  out[512 + (b0+b)*64 + d] = f;
  __syncthreads();
  if (d < 16){
    float a2 = hb[d];
    #pragma unroll
    for (int k=0; k<64; ++k) a2 += feat[k]*hw[d*64+k];
    out[(b0+b)*16 + d] = a2;
  }
}

// ======================= launch =======================
extern "C" void kernel_launch(void* const* d_in, const int* in_sizes, int n_in,
                              void* d_out, int out_size, void* d_ws, size_t ws_size,
                              hipStream_t stream)
{
  const float* x        = (const float*)d_in[0];
  const float* sconv_w  = (const float*)d_in[1];
  const float* bn1_g    = (const float*)d_in[2];
  const float* bn1_b    = (const float*)d_in[3];
  const float* bn1_m    = (const float*)d_in[4];
  const float* bn1_v    = (const float*)d_in[5];
  const float* tconv_w  = (const float*)d_in[6];
  const float* bn2_g    = (const float*)d_in[7];
  const float* bn2_b    = (const float*)d_in[8];
  const float* bn2_m    = (const float*)d_in[9];
  const float* bn2_v    = (const float*)d_in[10];
  const float* last_w   = (const float*)d_in[11];
  const float* ln1_g    = (const float*)d_in[12];
  const float* ln1_b    = (const float*)d_in[13];
  const float* in_proj_w= (const float*)d_in[14];
  const float* conv3d_w = (const float*)d_in[15];
  const float* conv3d_b = (const float*)d_in[16];
  const float* m_in_w   = (const float*)d_in[17];
  const float* m_conv_w = (const float*)d_in[18];
  const float* m_conv_b = (const float*)d_in[19];
  const float* m_xproj_w= (const float*)d_in[20];
  const float* m_dtproj_w=(const float*)d_in[21];
  const float* m_dtproj_b=(const float*)d_in[22];
  const float* m_Alog   = (const float*)d_in[23];
  const float* m_D      = (const float*)d_in[24];
  const float* m_out_w  = (const float*)d_in[25];
  const float* out_proj_w=(const float*)d_in[26];
  const float* ln2_g    = (const float*)d_in[27];
  const float* ln2_b    = (const float*)d_in[28];
  const float* fc1_w    = (const float*)d_in[29];
  const float* fc1_b    = (const float*)d_in[30];
  const float* fc2_w    = (const float*)d_in[31];
  const float* fc2_b    = (const float*)d_in[32];
  const float* head_w   = (const float*)d_in[33];
  const float* head_b   = (const float*)d_in[34];

  const size_t WB = 1345536;
  int nb = 1;
  for (int cand = 32; cand >= 1; cand >>= 1){
    size_t TPc = (((size_t)cand*LL + 63)/64)*64;
    size_t S2c = (size_t)2*cand*LL;
    size_t need = WB + TPc*2048 + S2c*672;
    if (need <= ws_size){ nb = cand; break; }
  }
  const size_t TP  = (((size_t)nb*LL + 63)/64)*64;
  const int S2  = 2*nb;
  const size_t S2T = (size_t)S2*LL;
  const int tokens = nb*LL;

  char* ws = (char*)d_ws;
  __hip_bfloat16* wbf   = (__hip_bfloat16*)(ws);
  size_t o = WB;
  __hip_bfloat16* xb    = (__hip_bfloat16*)(ws + o); o += TP*128;
  __hip_bfloat16* hx    = (__hip_bfloat16*)(ws + o); o += TP*128;
  float*          hp    = (float*)hx;
  __hip_bfloat16* xs    = (__hip_bfloat16*)(ws + o); o += TP*256;
  __hip_bfloat16* seq   = (__hip_bfloat16*)(ws + o); o += TP*256;
  __hip_bfloat16* ycomb = xs;
  float*          hfin  = (float*)xs;
  __hip_bfloat16* zblk  = (__hip_bfloat16*)(ws + o); o += TP*256;
  __hip_bfloat16* xm    = (__hip_bfloat16*)(ws + o);
  __hip_bfloat16* yo    = xm;                        o += TP*512;
  __hip_bfloat16* zm    = (__hip_bfloat16*)(ws + o);
  __hip_bfloat16* h2m   = zm;                        o += TP*512;
  float*          pre   = (float*)(ws + o);          o += S2T*160;
  __hip_bfloat16* ybuf  = (__hip_bfloat16*)(ws + o);
  float*          h1s   = (float*)(ws + o);
  float*          h2s   = (float*)(ws + o + (size_t)nb*495616);
  float*          sdtb  = hfin + (size_t)S2*NCH*4096;

  convert_weights<<<2624, 256, 0, stream>>>(in_proj_w, m_in_w, m_out_w, out_proj_w,
                                            fc1_w, fc2_w, m_xproj_w, wbf);

  const int gM2 = (int)((TP + 127)/128);

  for (int b0 = 0; b0 < 32; b0 += nb){
    stem1_kernel<<<nb*484, 256, 0, stream>>>(x, sconv_w, bn1_g, bn1_b, bn1_m, bn1_v, h1s, nb, b0);
    stem2_kernel<<<(nb*116160+255)/256, 256, 0, stream>>>(h1s, tconv_w, bn2_g, bn2_b, bn2_m, bn2_v, h2s, nb);
    stem3_kernel<<<(tokens*64+255)/256, 256, 0, stream>>>(h2s, last_w, xb, tokens);
    ln_kernel<<<(tokens+3)/4, 256, 0, stream>>>(xb, ln1_g, ln1_b, hx, tokens);

    for (int i = 0; i < 4; ++i){
      gemm_bf16<0><<<dim3(gM2,4), 256, 0, stream>>>(hx, wbf + i*16384, 64, 256, 128, tokens,
                                                    xs, zblk, nullptr, nullptr, nullptr, nullptr, nullptr);
      dwconv3d_kernel<<<(tokens*128+255)/256, 256, 0, stream>>>(xs, conv3d_w + i*3456, conv3d_b + i*128, seq, tokens);
      gemm_bf16<0><<<dim3(gM2,8), 256, 0, stream>>>(seq, wbf + 65536 + i*65536, 128, 512, 256, tokens,
                                                    xm, zm, nullptr, nullptr, nullptr, nullptr, nullptr);
      mamba_pre_kernel<<<S2*57, 256, 0, stream>>>(xm, m_conv_w + i*1024, m_conv_b + i*256,
                                                  wbf + 622592 + i*12288, ybuf, pre, nb);
      scan_p1<<<S2*NCH, 256, 0, stream>>>(ybuf, pre, m_dtproj_w + i*2048, m_dtproj_b + i*256,
                                          m_Alog + i*4096, hfin, sdtb);
      scan_comb<<<S2*16, 256, 0, stream>>>(m_Alog + i*4096, hfin, sdtb);
      scan_p2<<<S2*NCH, 256, 0, stream>>>(ybuf, pre, m_dtproj_w + i*2048, m_dtproj_b + i*256,
                                          m_Alog + i*4096, m_D + i*256, hfin);
      combine_kernel<<<(tokens*32+255)/256, 256, 0, stream>>>(ybuf, zm, ycomb, tokens, nb);
      gemm_bf16<4><<<dim3(gM2,2), 256, 0, stream>>>(ycomb, wbf + 327680 + i*32768, 256, 128, 0, tokens,
                                                    yo, nullptr, nullptr, zblk, nullptr, nullptr, nullptr);
      // out_proj + residual + LN2 fused -> hx
      gemm_bf16<5><<<dim3(gM2,1), 256, 0, stream>>>(yo, wbf + 458752 + i*8192, 128, 64, 0, tokens,
                                                    hx, nullptr, nullptr, nullptr, xb,
                                                    ln2_g + i*64, ln2_b + i*64);
      gemm_bf16<2><<<dim3(gM2,4), 256, 0, stream>>>(hx, wbf + 491520 + i*16384, 64, 256, 0, tokens,
                                                    h2m, nullptr, fc1_b + i*256, nullptr, nullptr, nullptr, nullptr);
      // fc2 + residual + next-layer LN1 fused -> hx (unused at i==3)
      int inext = (i < 3) ? i+1 : 3;
      gemm_bf16<5><<<dim3(gM2,1), 256, 0, stream>>>(h2m, wbf + 557056 + i*16384, 256, 64, 0, tokens,
                                                    hx, nullptr, fc2_b + i*64, nullptr, xb,
                                                    ln1_g + inext*64, ln1_b + inext*64);
    }
    head1_kernel<<<nb*30, 256, 0, stream>>>(xb, hp);
    head2_kernel<<<nb, 64, 0, stream>>>(hp, head_w, head_b, (float*)d_out, b0);
  }
}

// Round 8
// 6192.474 us; speedup vs baseline: 4.8427x; 1.0829x over previous
//
#include <hip/hip_runtime.h>
#include <hip/hip_bf16.h>
#include <hip/hip_fp16.h>

#define LL    3630
#define EPSV  1e-5f
#define NCH   57      // scan chunks (64-token, matches mamba_pre blocks)
#define CLEN  64

typedef short bf16x8 __attribute__((ext_vector_type(8)));
typedef float f32x4  __attribute__((ext_vector_type(4)));
typedef float f32x2  __attribute__((ext_vector_type(2)));
typedef float f32x16 __attribute__((ext_vector_type(16)));

__device__ __forceinline__ float bf2f(__hip_bfloat16 x){ return __bfloat162float(x); }
__device__ __forceinline__ __hip_bfloat16 f2bf(float x){ return __float2bfloat16(x); }
__device__ __forceinline__ float siluf(float x){ return x / (1.f + __expf(-x)); }
__device__ __forceinline__ float s2f(short s){ __hip_bfloat16 t = __builtin_bit_cast(__hip_bfloat16, s); return __bfloat162float(t); }
__device__ __forceinline__ short f2s(float x){ __hip_bfloat16 t = __float2bfloat16(x); return __builtin_bit_cast(short, t); }

// ======================= weight f32 -> bf16 =======================
__global__ __launch_bounds__(256) void convert_weights(
    const float* __restrict__ s0, const float* __restrict__ s1,
    const float* __restrict__ s2, const float* __restrict__ s3,
    const float* __restrict__ s4, const float* __restrict__ s5,
    const float* __restrict__ s6,
    __hip_bfloat16* __restrict__ dst)
{
  int gid = blockIdx.x*256 + threadIdx.x;
  float v;
  if      (gid <  65536) v = s0[gid];
  else if (gid < 327680) v = s1[gid-65536];
  else if (gid < 458752) v = s2[gid-327680];
  else if (gid < 491520) v = s3[gid-458752];
  else if (gid < 557056) v = s4[gid-491520];
  else if (gid < 622592) v = s5[gid-557056];
  else if (gid < 671744){
    int rel = gid - 622592;
    int layer = rel / 12288;
    int rr  = (rel % 12288) / 256;
    int ccol= rel & 255;
    v = (rr < 40) ? s6[layer*10240 + rr*256 + ccol] : 0.f;
  }
  else return;
  dst[gid] = f2bf(v);
}

// ======================= stem =======================
__global__ __launch_bounds__(256) void stem1_kernel(
    const float* __restrict__ x, const float* __restrict__ w,
    const float* __restrict__ g, const float* __restrict__ bb,
    const float* __restrict__ mm, const float* __restrict__ vv,
    float* __restrict__ out, int nb, int b0)
{
  int idx = blockIdx.x*256 + threadIdx.x;
  if (idx >= nb*123904) return;
  int j = idx % 11;
  int i = (idx/11) % 11;
  int t = (idx/121) % 32;
  int c = (idx/(121*32)) % 32;
  int b = idx/(121*32*32);
  const float* xp = x + ((b0+b)*32 + t)*169;
  const float* wp = w + c*9;
  float acc = 0.f;
  #pragma unroll
  for (int di=0; di<3; ++di)
    #pragma unroll
    for (int dj=0; dj<3; ++dj)
      acc += xp[(i+di)*13 + (j+dj)] * wp[di*3+dj];
  float s = g[c]*rsqrtf(vv[c]+EPSV);
  acc = acc*s + (bb[c]-mm[c]*s);
  out[idx] = fmaxf(acc, 0.f);
}

__global__ __launch_bounds__(256) void stem2_kernel(
    const float* __restrict__ h1, const float* __restrict__ w,
    const float* __restrict__ g, const float* __restrict__ bb,
    const float* __restrict__ mm, const float* __restrict__ vv,
    float* __restrict__ out, int nb)
{
  int idx = blockIdx.x*256 + threadIdx.x;
  if (idx >= nb*116160) return;
  int ij = idx % 121;
  int t  = (idx/121) % 30;
  int c  = (idx/(121*30)) % 32;
  int b  = idx/(121*30*32);
  const float* hp = h1 + ((b*32+c)*32)*121 + ij;
  const float* wp = w + c*3;
  float acc = 0.f;
  #pragma unroll
  for (int k=0;k<3;++k) acc += hp[(t+k)*121] * wp[k];
  float s = g[c]*rsqrtf(vv[c]+EPSV);
  acc = acc*s + (bb[c]-mm[c]*s);
  out[idx] = fmaxf(acc, 0.f);
}

__global__ __launch_bounds__(256) void stem3_kernel(
    const float* __restrict__ h2, const float* __restrict__ w,
    __hip_bfloat16* __restrict__ xb, int tokens)
{
  int gid = blockIdx.x*256 + threadIdx.x;
  int cc = gid & 63;
  int tok = gid >> 6;
  if (tok >= tokens) return;
  int ij = tok % 121;
  int t  = (tok/121) % 30;
  int b  = tok/LL;
  const float* hp = h2 + ((long)b*32)*30*121 + t*121 + ij;
  const float* wp = w + cc*32;
  float acc = 0.f;
  #pragma unroll
  for (int ci=0; ci<32; ++ci) acc += hp[ci*3630] * wp[ci];
  xb[(long)tok*64+cc] = f2bf(acc);
}

// ======================= layernorm (dim 64) — used once per pass =======================
__global__ __launch_bounds__(256) void ln_kernel(
    const __hip_bfloat16* __restrict__ xb, const float* __restrict__ g,
    const float* __restrict__ b2, __hip_bfloat16* __restrict__ out, int tokens)
{
  int wid = threadIdx.x >> 6, lane = threadIdx.x & 63;
  long tok = (long)blockIdx.x*4 + wid;
  if (tok >= tokens) return;
  float v = bf2f(xb[tok*64 + lane]);
  float s = v, q = v*v;
  #pragma unroll
  for (int m=1; m<64; m<<=1){ s += __shfl_xor(s,m); q += __shfl_xor(q,m); }
  float mean = s*(1.f/64.f);
  float var  = q*(1.f/64.f) - mean*mean;
  float o = (v-mean)*rsqrtf(var+EPSV)*g[lane] + b2[lane];
  out[tok*64+lane] = f2bf(o);
}

// ======================= bf16 MFMA GEMM: out[M,N] = A[M,K] @ W[N,K]^T =======================
// EPI 0: split silu; EPI 2: bias+gelu; EPI 3: (+bias)+resid RMW; EPI 4: gate;
// EPI 5 (N=64): (+bias)+resid RMW -> resid, then LayerNorm(lng,lnb) -> out1
template<int EPI>
__global__ __launch_bounds__(256) void gemm_bf16(
    const __hip_bfloat16* __restrict__ A, const __hip_bfloat16* __restrict__ W,
    int K, int N, int NH, int tokens,
    __hip_bfloat16* __restrict__ out1, __hip_bfloat16* __restrict__ out2,
    const float* __restrict__ bias, const __hip_bfloat16* __restrict__ gate,
    __hip_bfloat16* __restrict__ resid,
    const float* __restrict__ lng, const float* __restrict__ lnb)
{
  int w   = threadIdx.x >> 6;
  int lane= threadIdx.x & 63;
  int r16 = lane & 15;
  int kg  = lane >> 4;          // 0..3
  long m0 = (long)blockIdx.x*128 + w*32;
  int  n0 = blockIdx.y*64;
  long ra0 = m0 + r16;      if (ra0 > tokens-1) ra0 = tokens-1;
  long ra1 = m0 + 16 + r16; if (ra1 > tokens-1) ra1 = tokens-1;
  f32x4 acc[2][4] = { { {0,0,0,0},{0,0,0,0},{0,0,0,0},{0,0,0,0} },
                      { {0,0,0,0},{0,0,0,0},{0,0,0,0},{0,0,0,0} } };
  for (int k0 = 0; k0 < K; k0 += 32){
    bf16x8 a0 = *reinterpret_cast<const bf16x8*>(A + ra0*K + k0 + kg*8);
    bf16x8 a1 = *reinterpret_cast<const bf16x8*>(A + ra1*K + k0 + kg*8);
    #pragma unroll
    for (int f=0; f<4; ++f){
      bf16x8 b = *reinterpret_cast<const bf16x8*>(W + (long)(n0 + f*16 + r16)*K + k0 + kg*8);
      acc[0][f] = __builtin_amdgcn_mfma_f32_16x16x32_bf16(a0, b, acc[0][f], 0, 0, 0);
      acc[1][f] = __builtin_amdgcn_mfma_f32_16x16x32_bf16(a1, b, acc[1][f], 0, 0, 0);
    }
  }
  if (EPI == 5){
    float gv[4], bv[4], biasv[4];
    #pragma unroll
    for (int f=0; f<4; ++f){
      gv[f] = lng[f*16+r16]; bv[f] = lnb[f*16+r16];
      biasv[f] = bias ? bias[f*16+r16] : 0.f;
    }
    #pragma unroll
    for (int g2=0; g2<2; ++g2){
      #pragma unroll
      for (int r=0; r<4; ++r){
        long row = m0 + g2*16 + kg*4 + r;
        bool ok = row < tokens;
        long rowc = ok ? row : (tokens-1);
        float v[4]; float s = 0.f, q = 0.f;
        #pragma unroll
        for (int f=0; f<4; ++f){
          float t = acc[g2][f][r] + biasv[f] + bf2f(resid[rowc*64 + f*16+r16]);
          v[f] = t; s += t; q += t*t;
        }
        #pragma unroll
        for (int m=1; m<16; m<<=1){ s += __shfl_xor(s,m); q += __shfl_xor(q,m); }
        float mean = s*(1.f/64.f);
        float var  = q*(1.f/64.f) - mean*mean;
        float rstd = rsqrtf(var+EPSV);
        if (ok){
          #pragma unroll
          for (int f=0; f<4; ++f){
            resid[row*64 + f*16+r16] = f2bf(v[f]);
            out1 [row*64 + f*16+r16] = f2bf((v[f]-mean)*rstd*gv[f] + bv[f]);
          }
        }
      }
    }
    return;
  }
  #pragma unroll
  for (int g2=0; g2<2; ++g2){
    #pragma unroll
    for (int f=0; f<4; ++f){
      int col = n0 + f*16 + r16;
      #pragma unroll
      for (int r=0; r<4; ++r){
        long row = m0 + g2*16 + kg*4 + r;
        if (row >= tokens) continue;
        float v = acc[g2][f][r];
        if (EPI == 0){
          if (col < NH) out1[row*NH + col] = f2bf(v);
          else          out2[row*NH + col - NH] = f2bf(siluf(v));
        } else if (EPI == 2){
          v += bias[col];
          v = 0.5f*v*(1.f + erff(v*0.70710678118f));
          out1[row*N + col] = f2bf(v);
        } else if (EPI == 3){
          if (bias) v += bias[col];
          resid[row*N + col] = f2bf(v + bf2f(resid[row*N + col]));
        } else {
          out1[row*N + col] = f2bf(v * bf2f(gate[row*N + col]));
        }
      }
    }
  }
}

// ======================= depthwise conv3d 3x3x3 SAME + silu =======================
__global__ __launch_bounds__(256) void dwconv3d_kernel(
    const __hip_bfloat16* __restrict__ xs, const float* __restrict__ w,
    const float* __restrict__ bias, __hip_bfloat16* __restrict__ seq, int tokens)
{
  long gid = (long)blockIdx.x*256 + threadIdx.x;
  int c = gid & 127;
  long tok = gid >> 7;
  if (tok >= tokens) return;
  int j  = tok % 11;
  int i2 = (tok/11) % 11;
  int t  = (tok/121) % 30;
  long b = tok/LL;
  const float* wc = w + c*27;
  float acc = bias[c];
  #pragma unroll
  for (int dt=0; dt<3; ++dt){
    int tt = t+dt-1; if (tt<0 || tt>=30) continue;
    #pragma unroll
    for (int di=0; di<3; ++di){
      int ii = i2+di-1; if (ii<0 || ii>=11) continue;
      #pragma unroll
      for (int dj=0; dj<3; ++dj){
        int jj = j+dj-1; if (jj<0 || jj>=11) continue;
        long t2 = (b*30+tt)*121 + ii*11 + jj;
        acc += wc[dt*9+di*3+dj] * bf2f(xs[t2*128 + c]);
      }
    }
  }
  seq[tok*128 + c] = f2bf(siluf(acc));
}

// ======================= mamba_pre + scan pass1 fused =======================
// block = one 64-token chunk of one direction-sequence; 256 threads
// phase 1: conv1d+silu -> xcs LDS + ub global
// phase 2: xproj MFMA -> pre global + pres LDS
// phase 3: per-thread-d scan of chunk -> hfin, sdt
__global__ __launch_bounds__(256) void mamba_pre_scan(
    const __hip_bfloat16* __restrict__ xm,
    const float* __restrict__ cw, const float* __restrict__ cbv,
    const __hip_bfloat16* __restrict__ xpw_bf,
    const float* __restrict__ dtw, const float* __restrict__ dtbv,
    const float* __restrict__ Alog,
    __hip_bfloat16* __restrict__ ub,
    float* __restrict__ pre,
    float* __restrict__ hfin, float* __restrict__ sdt,
    int nb)
{
  __shared__ __hip_bfloat16 xcs[64][264];
  __shared__ float pres[64][44];          // rows 176B -> 16B aligned
  int s  = blockIdx.x / NCH;
  int ch = blockIdx.x % NCH;
  int p0 = ch*CLEN;
  int b  = s % nb;
  bool fwd = s < nb;
  int d = threadIdx.x;
  const long basex = (long)b*LL*256 + d;
  const long sLL = (long)s*LL;
  {
    float w0=cw[d*4], w1=cw[d*4+1], w2=cw[d*4+2], w3=cw[d*4+3], cb=cbv[d];
    float p1=0.f, p2=0.f, p3=0.f;
    if (p0-1 >= 0) p1 = bf2f(xm[basex + (long)(fwd ? p0-1 : LL-p0  )*256]);
    if (p0-2 >= 0) p2 = bf2f(xm[basex + (long)(fwd ? p0-2 : LL+1-p0)*256]);
    if (p0-3 >= 0) p3 = bf2f(xm[basex + (long)(fwd ? p0-3 : LL+2-p0)*256]);
    for (int t=0; t<64; ++t){
      int p = p0 + t;
      float xl = 0.f;
      if (p < LL) xl = bf2f(xm[basex + (long)(fwd ? p : LL-1-p)*256]);
      float xc = w3*xl + w2*p1 + w1*p2 + w0*p3 + cb;
      p3=p2; p2=p1; p1=xl;
      __hip_bfloat16 uv = f2bf(siluf(xc));
      xcs[t][d] = uv;
      if (p < LL) ub[(sLL + p)*256 + d] = uv;
    }
  }
  __syncthreads();
  {
    int w = threadIdx.x >> 6, lane = threadIdx.x & 63;
    int r16 = lane & 15, kg = lane >> 4;
    int t0 = w*16;
    f32x4 acc[3] = { {0,0,0,0},{0,0,0,0},{0,0,0,0} };
    for (int k0=0; k0<256; k0+=32){
      bf16x8 a = *reinterpret_cast<const bf16x8*>(&xcs[t0+r16][k0+kg*8]);
      #pragma unroll
      for (int f=0; f<3; ++f){
        bf16x8 bb = *reinterpret_cast<const bf16x8*>(xpw_bf + (f*16+r16)*256 + k0 + kg*8);
        acc[f] = __builtin_amdgcn_mfma_f32_16x16x32_bf16(a, bb, acc[f], 0, 0, 0);
      }
    }
    #pragma unroll
    for (int f=0; f<3; ++f){
      int col = f*16 + r16;
      #pragma unroll
      for (int r=0; r<4; ++r){
        int tl = t0 + kg*4 + r;
        int p = p0 + tl;
        if (col < 40){
          pres[tl][col] = acc[f][r];
          if (p < LL) pre[(sLL + p)*40 + col] = acc[f][r];
        }
      }
    }
  }
  __syncthreads();
  {
    int lim = LL - p0; if (lim > CLEN) lim = CLEN;
    f32x2 a2[8], h[8];
    #pragma unroll
    for (int k=0;k<8;++k){
      a2[k] = (f32x2){ -__expf(Alog[d*16+2*k])*1.44269504f,
                       -__expf(Alog[d*16+2*k+1])*1.44269504f };
      h[k] = (f32x2){0.f, 0.f};
    }
    float dw[8];
    #pragma unroll
    for (int r=0;r<8;++r) dw[r] = dtw[d*8+r];
    float dtb_d = dtbv[d];
    float sacc = 0.f;
    for (int t=0; t<lim; ++t){
      float u = bf2f(xcs[t][d]);
      float4 r0 = *reinterpret_cast<const float4*>(&pres[t][0]);
      float4 r1 = *reinterpret_cast<const float4*>(&pres[t][4]);
      float xacc = dtb_d;
      xacc = fmaf(r0.x,dw[0],fmaf(r0.y,dw[1],fmaf(r0.z,dw[2],fmaf(r0.w,dw[3],xacc))));
      xacc = fmaf(r1.x,dw[4],fmaf(r1.y,dw[5],fmaf(r1.z,dw[6],fmaf(r1.w,dw[7],xacc))));
      float dt = (xacc > 20.f) ? xacc : __logf(1.f + __expf(xacc));
      sacc += dt;
      float4 B0 = *reinterpret_cast<const float4*>(&pres[t][8]);
      float4 B1 = *reinterpret_cast<const float4*>(&pres[t][12]);
      float4 B2 = *reinterpret_cast<const float4*>(&pres[t][16]);
      float4 B3 = *reinterpret_cast<const float4*>(&pres[t][20]);
      float Bv[16] = {B0.x,B0.y,B0.z,B0.w,B1.x,B1.y,B1.z,B1.w,
                      B2.x,B2.y,B2.z,B2.w,B3.x,B3.y,B3.z,B3.w};
      f32x2 dt2  = (f32x2){dt, dt};
      float dtu = dt*u;
      f32x2 dtu2 = (f32x2){dtu, dtu};
      #pragma unroll
      for (int k=0;k<8;++k){
        f32x2 tt = dt2*a2[k];
        f32x2 e = (f32x2){ exp2f(tt.x), exp2f(tt.y) };
        f32x2 bk = (f32x2){ Bv[2*k], Bv[2*k+1] };
        h[k] = __builtin_elementwise_fma(e, h[k], dtu2*bk);
      }
    }
    long hbase = ((long)blockIdx.x*256 + d)*16;   // blockIdx.x == s*NCH+ch
    #pragma unroll
    for (int k=0;k<8;++k){ hfin[hbase+2*k] = h[k].x; hfin[hbase+2*k+1] = h[k].y; }
    sdt[(long)blockIdx.x*256 + d] = sacc;
  }
}

// sequential chunk combine (in-place: hfin becomes hinit)
__global__ __launch_bounds__(256) void scan_comb(
    const float* __restrict__ Alog,
    float* __restrict__ hfin, const float* __restrict__ sdt)
{
  int s = blockIdx.x >> 4, dg = blockIdx.x & 15;
  int d = dg*16 + (threadIdx.x >> 4), n = threadIdx.x & 15;
  float a2 = -__expf(Alog[d*16+n]) * 1.44269504f;
  float h = 0.f;
  for (int ch=0; ch<NCH; ++ch){
    long sc = (long)s*NCH + ch;
    long idx = (sc*256 + d)*16 + n;
    float hf = hfin[idx];
    float sd = sdt[sc*256 + d];
    hfin[idx] = h;
    h = exp2f(a2*sd)*h + hf;
  }
}

// pass2: rescan chunk from hinit; write raw y (+u*D) over ub in-place
__global__ __launch_bounds__(256) void scan_p2(
    __hip_bfloat16* __restrict__ ub,
    const float* __restrict__ pre,
    const float* __restrict__ dtw, const float* __restrict__ dtbv,
    const float* __restrict__ Alog, const float* __restrict__ Dv,
    const float* __restrict__ hinit)
{
  int d = threadIdx.x;
  int sc = blockIdx.x;
  int ch = sc % NCH, s = sc / NCH;
  int l0 = ch*CLEN;
  int lim = LL - l0; if (lim > CLEN) lim = CLEN;
  f32x2 a2[8], h[8];
  long hbase = ((long)sc*256 + d)*16;
  #pragma unroll
  for (int k=0;k<8;++k){
    a2[k] = (f32x2){ -__expf(Alog[d*16+2*k])*1.44269504f,
                     -__expf(Alog[d*16+2*k+1])*1.44269504f };
    h[k] = (f32x2){ hinit[hbase+2*k], hinit[hbase+2*k+1] };
  }
  float dw[8];
  #pragma unroll
  for (int r=0;r<8;++r) dw[r] = dtw[d*8+r];
  float dtb_d = dtbv[d];
  float dpv = Dv[d];
  long tok0 = (long)s*LL + l0;
  long ui = tok0*256 + d;
  long pi = tok0*40;
  for (int l=0; l<lim; ++l){
    float u = bf2f(ub[ui]);
    float4 r0 = *reinterpret_cast<const float4*>(pre+pi);
    float4 r1 = *reinterpret_cast<const float4*>(pre+pi+4);
    float xacc = dtb_d;
    xacc = fmaf(r0.x,dw[0],fmaf(r0.y,dw[1],fmaf(r0.z,dw[2],fmaf(r0.w,dw[3],xacc))));
    xacc = fmaf(r1.x,dw[4],fmaf(r1.y,dw[5],fmaf(r1.z,dw[6],fmaf(r1.w,dw[7],xacc))));
    float dt = (xacc > 20.f) ? xacc : __logf(1.f + __expf(xacc));
    f32x16 B = *reinterpret_cast<const f32x16*>(pre+pi+8);
    f32x16 C = *reinterpret_cast<const f32x16*>(pre+pi+24);
    f32x2 dt2  = (f32x2){dt, dt};
    float dtu = dt*u;
    f32x2 dtu2 = (f32x2){dtu, dtu};
    f32x2 y2 = (f32x2){0.f, 0.f};
    #pragma unroll
    for (int k=0;k<8;++k){
      f32x2 t = dt2*a2[k];
      f32x2 e = (f32x2){ exp2f(t.x), exp2f(t.y) };
      f32x2 bk = (f32x2){ B[2*k], B[2*k+1] };
      f32x2 ck = (f32x2){ C[2*k], C[2*k+1] };
      h[k] = __builtin_elementwise_fma(e, h[k], dtu2*bk);
      y2 = __builtin_elementwise_fma(h[k], ck, y2);
    }
    float y = y2.x + y2.y;
    ub[ui] = f2bf(y + u*dpv);
    ui += 256; pi += 40;
  }
}

// ======================= combine fwd/bwd + zm gate (bf16x8 vectorized) =======================
__global__ __launch_bounds__(256) void combine_kernel(
    const __hip_bfloat16* __restrict__ yb, const __hip_bfloat16* __restrict__ zm,
    __hip_bfloat16* __restrict__ ycomb, int tokens, int nb)
{
  long gid = (long)blockIdx.x*256 + threadIdx.x;   // one per 8 channels
  long tok = gid >> 5;
  if (tok >= tokens) return;
  int c8 = (gid & 31) * 8;
  long l = tok % LL, b = tok / LL;
  bf16x8 vf = *reinterpret_cast<const bf16x8*>(yb + ( b*LL + l)*256 + c8);
  bf16x8 vb = *reinterpret_cast<const bf16x8*>(yb + ((nb+b)*LL + (LL-1-l))*256 + c8);
  bf16x8 zz = *reinterpret_cast<const bf16x8*>(zm + tok*256 + c8);
  bf16x8 out;
  #pragma unroll
  for (int k=0;k<8;++k){
    float r = (s2f(vf[k]) + s2f(vb[k])) * s2f(zz[k]);
    out[k] = f2s(r);
  }
  *reinterpret_cast<bf16x8*>(ycomb + tok*256 + c8) = out;
}

// ======================= head: two-stage mean + linear =======================
__global__ __launch_bounds__(256) void head1_kernel(
    const __hip_bfloat16* __restrict__ xb, float* __restrict__ hp)
{
  __shared__ float partial[4][64];
  int b = blockIdx.x / 30, ch = blockIdx.x % 30;
  int d = threadIdx.x & 63, part = threadIdx.x >> 6;
  float acc = 0.f;
  int lend = (ch+1)*121;
  for (int l = ch*121 + part; l < lend; l += 4)
    acc += bf2f(xb[((long)b*LL + l)*64 + d]);
  partial[part][d] = acc;
  __syncthreads();
  if (part == 0)
    hp[(b*30 + ch)*64 + d] = partial[0][d]+partial[1][d]+partial[2][d]+partial[3][d];
}

__global__ __launch_bounds__(64) void head2_kernel(
    const float* __restrict__ hp, const float* __restrict__ hw,
    const float* __restrict__ hb, float* __restrict__ out, int b0)
{
  __shared__ float feat[64];
  int b = blockIdx.x;
  int d = threadIdx.x;
  float acc = 0.f;
  #pragma unroll
  for (int ch=0; ch<30; ++ch) acc += hp[(b*30+ch)*64 + d];
  float f = acc * (1.f/3630.f);
  feat[d] = f;
  out[512 + (b0+b)*64 + d] = f;
  __syncthreads();
  if (d < 16){
    float a2 = hb[d];
    #pragma unroll
    for (int k=0; k<64; ++k) a2 += feat[k]*hw[d*64+k];
    out[(b0+b)*16 + d] = a2;
  }
}

// ======================= launch =======================
extern "C" void kernel_launch(void* const* d_in, const int* in_sizes, int n_in,
                              void* d_out, int out_size, void* d_ws, size_t ws_size,
                              hipStream_t stream)
{
  const float* x        = (const float*)d_in[0];
  const float* sconv_w  = (const float*)d_in[1];
  const float* bn1_g    = (const float*)d_in[2];
  const float* bn1_b    = (const float*)d_in[3];
  const float* bn1_m    = (const float*)d_in[4];
  const float* bn1_v    = (const float*)d_in[5];
  const float* tconv_w  = (const float*)d_in[6];
  const float* bn2_g    = (const float*)d_in[7];
  const float* bn2_b    = (const float*)d_in[8];
  const float* bn2_m    = (const float*)d_in[9];
  const float* bn2_v    = (const float*)d_in[10];
  const float* last_w   = (const float*)d_in[11];
  const float* ln1_g    = (const float*)d_in[12];
  const float* ln1_b    = (const float*)d_in[13];
  const float* in_proj_w= (const float*)d_in[14];
  const float* conv3d_w = (const float*)d_in[15];
  const float* conv3d_b = (const float*)d_in[16];
  const float* m_in_w   = (const float*)d_in[17];
  const float* m_conv_w = (const float*)d_in[18];
  const float* m_conv_b = (const float*)d_in[19];
  const float* m_xproj_w= (const float*)d_in[20];
  const float* m_dtproj_w=(const float*)d_in[21];
  const float* m_dtproj_b=(const float*)d_in[22];
  const float* m_Alog   = (const float*)d_in[23];
  const float* m_D      = (const float*)d_in[24];
  const float* m_out_w  = (const float*)d_in[25];
  const float* out_proj_w=(const float*)d_in[26];
  const float* ln2_g    = (const float*)d_in[27];
  const float* ln2_b    = (const float*)d_in[28];
  const float* fc1_w    = (const float*)d_in[29];
  const float* fc1_b    = (const float*)d_in[30];
  const float* fc2_w    = (const float*)d_in[31];
  const float* fc2_b    = (const float*)d_in[32];
  const float* head_w   = (const float*)d_in[33];
  const float* head_b   = (const float*)d_in[34];

  const size_t WB = 1345536;
  int nb = 1;
  for (int cand = 32; cand >= 1; cand >>= 1){
    size_t TPc = (((size_t)cand*LL + 63)/64)*64;
    size_t S2c = (size_t)2*cand*LL;
    size_t need = WB + TPc*2048 + S2c*672;
    if (need <= ws_size){ nb = cand; break; }
  }
  const size_t TP  = (((size_t)nb*LL + 63)/64)*64;
  const int S2  = 2*nb;
  const size_t S2T = (size_t)S2*LL;
  const int tokens = nb*LL;

  char* ws = (char*)d_ws;
  __hip_bfloat16* wbf   = (__hip_bfloat16*)(ws);
  size_t o = WB;
  __hip_bfloat16* xb    = (__hip_bfloat16*)(ws + o); o += TP*128;
  __hip_bfloat16* hx    = (__hip_bfloat16*)(ws + o); o += TP*128;
  float*          hp    = (float*)hx;
  float*          hfin  = (float*)hx;       // spans hx+xs+seq during scan phase
  __hip_bfloat16* xs    = (__hip_bfloat16*)(ws + o); o += TP*256;
  __hip_bfloat16* seq   = (__hip_bfloat16*)(ws + o); o += TP*256;
  __hip_bfloat16* ycomb = xs;
  __hip_bfloat16* zblk  = (__hip_bfloat16*)(ws + o); o += TP*256;
  __hip_bfloat16* xm    = (__hip_bfloat16*)(ws + o);
  __hip_bfloat16* yo    = xm;                        o += TP*512;
  __hip_bfloat16* zm    = (__hip_bfloat16*)(ws + o);
  __hip_bfloat16* h2m   = zm;                        o += TP*512;
  float*          pre   = (float*)(ws + o);          o += S2T*160;
  __hip_bfloat16* ybuf  = (__hip_bfloat16*)(ws + o);
  float*          h1s   = (float*)(ws + o);
  float*          h2s   = (float*)(ws + o + (size_t)nb*495616);
  float*          sdtb  = hfin + (size_t)S2*NCH*4096;

  convert_weights<<<2624, 256, 0, stream>>>(in_proj_w, m_in_w, m_out_w, out_proj_w,
                                            fc1_w, fc2_w, m_xproj_w, wbf);

  const int gM2 = (int)((TP + 127)/128);

  for (int b0 = 0; b0 < 32; b0 += nb){
    stem1_kernel<<<nb*484, 256, 0, stream>>>(x, sconv_w, bn1_g, bn1_b, bn1_m, bn1_v, h1s, nb, b0);
    stem2_kernel<<<(nb*116160+255)/256, 256, 0, stream>>>(h1s, tconv_w, bn2_g, bn2_b, bn2_m, bn2_v, h2s, nb);
    stem3_kernel<<<(tokens*64+255)/256, 256, 0, stream>>>(h2s, last_w, xb, tokens);
    ln_kernel<<<(tokens+3)/4, 256, 0, stream>>>(xb, ln1_g, ln1_b, hx, tokens);

    for (int i = 0; i < 4; ++i){
      gemm_bf16<0><<<dim3(gM2,4), 256, 0, stream>>>(hx, wbf + i*16384, 64, 256, 128, tokens,
                                                    xs, zblk, nullptr, nullptr, nullptr, nullptr, nullptr);
      dwconv3d_kernel<<<(tokens*128+255)/256, 256, 0, stream>>>(xs, conv3d_w + i*3456, conv3d_b + i*128, seq, tokens);
      gemm_bf16<0><<<dim3(gM2,8), 256, 0, stream>>>(seq, wbf + 65536 + i*65536, 128, 512, 256, tokens,
                                                    xm, zm, nullptr, nullptr, nullptr, nullptr, nullptr);
      mamba_pre_scan<<<S2*NCH, 256, 0, stream>>>(xm, m_conv_w + i*1024, m_conv_b + i*256,
                                                 wbf + 622592 + i*12288,
                                                 m_dtproj_w + i*2048, m_dtproj_b + i*256,
                                                 m_Alog + i*4096,
                                                 ybuf, pre, hfin, sdtb, nb);
      scan_comb<<<S2*16, 256, 0, stream>>>(m_Alog + i*4096, hfin, sdtb);
      scan_p2<<<S2*NCH, 256, 0, stream>>>(ybuf, pre, m_dtproj_w + i*2048, m_dtproj_b + i*256,
                                          m_Alog + i*4096, m_D + i*256, hfin);
      combine_kernel<<<(tokens*32+255)/256, 256, 0, stream>>>(ybuf, zm, ycomb, tokens, nb);
      gemm_bf16<4><<<dim3(gM2,2), 256, 0, stream>>>(ycomb, wbf + 327680 + i*32768, 256, 128, 0, tokens,
                                                    yo, nullptr, nullptr, zblk, nullptr, nullptr, nullptr);
      gemm_bf16<5><<<dim3(gM2,1), 256, 0, stream>>>(yo, wbf + 458752 + i*8192, 128, 64, 0, tokens,
                                                    hx, nullptr, nullptr, nullptr, xb,
                                                    ln2_g + i*64, ln2_b + i*64);
      gemm_bf16<2><<<dim3(gM2,4), 256, 0, stream>>>(hx, wbf + 491520 + i*16384, 64, 256, 0, tokens,
                                                    h2m, nullptr, fc1_b + i*256, nullptr, nullptr, nullptr, nullptr);
      int inext = (i < 3) ? i+1 : 3;
      gemm_bf16<5><<<dim3(gM2,1), 256, 0, stream>>>(h2m, wbf + 557056 + i*16384, 256, 64, 0, tokens,
                                                    hx, nullptr, fc2_b + i*64, nullptr, xb,
                                                    ln1_g + inext*64, ln1_b + inext*64);
    }
    head1_kernel<<<nb*30, 256, 0, stream>>>(xb, hp);
    head2_kernel<<<nb, 64, 0, stream>>>(hp, head_w, head_b, (float*)d_out, b0);
  }
}